// Round 5
// baseline (3535.730 us; speedup 1.0000x reference)
//
#include <hip/hip_runtime.h>

typedef unsigned short u16;
typedef unsigned int u32;

#define DEVI static __device__ __forceinline__

#define SS 512
#define DD 512
#define NFF 2048
#define VV 32000
#define MTOT 4096
#define HD 4096

DEVI float bf2f(u16 h){ return __uint_as_float(((u32)h) << 16); }
DEVI u16 f2bf(float f){
  u32 u = __float_as_uint(f);
  return (u16)((u + 0x7FFFu + ((u >> 16) & 1u)) >> 16);
}
DEVI float ldf(const void* p, long i, int isbf){
  return isbf ? bf2f(((const u16*)p)[i]) : ((const float*)p)[i];
}

DEVI float wave_redmax(float v){
  #pragma unroll
  for (int off = 32; off > 0; off >>= 1) v = fmaxf(v, __shfl_xor(v, off, 64));
  return v;
}
DEVI float wave_redsum(float v){
  #pragma unroll
  for (int off = 32; off > 0; off >>= 1) v += __shfl_xor(v, off, 64);
  return v;
}

// pe row0 = [sin0=0, cos0=1, ...]: first u32 word = 0x3F800000 if bf16, 0x00000000 if f32
__global__ void k_dflag(const void* pe, int* flag){
  flag[0] = (*(const u32*)pe == 0x3F800000u) ? 1 : 0;
}

__global__ __launch_bounds__(256) void k_embed(
    const int* __restrict__ tok, const void* __restrict__ emb, const void* __restrict__ pe,
    float* __restrict__ x, float* __restrict__ xm, const int* __restrict__ dflag)
{
  int isbf = dflag[0];
  int blk = blockIdx.x;
  int s = blk & (SS - 1);
  int t = tok[blk];
  long base = (long)blk * DD;
  for (int d = threadIdx.x; d < DD; d += 256){
    float e = ldf(emb, (long)t * DD + d, isbf) + ldf(pe, (long)s * DD + d, isbf);
    x[base + d] = e;
    xm[base + d] = (d <= s) ? e : 0.f;   // triu(ones(S,D),k=1) zeroes d > s
  }
}

// All-f32 NN GEMM: C = A[M,K] @ B[K,N] (B row-major [K][N] = weights as stored).
// 64x64 tile, 256 threads, 4x4 acc/thread.
// MODE 0 QPROJ : C[(zl*8+b)*S*D + s*D + n] = c + bias[zi*D+n]      (also used for V)
// MODE 1 KPROJ : C[((zl*8+b)*D + n)*S + s] = c + bias[zi*D+n]
// MODE 2 SCORE : C[zl*S*S + s*S + t] = c * scale
// MODE 3 PV    : cat[(b*S + s)*HD + (zoff + h)*D + n] = c            (zl = h*8+b)
// MODE 4 FF1   : C[m*N + n] = relu(c + bias[n])
// MODE 5 FF2RES: C[m*N + n] = c + bias[n] + res[m*N + n]
// MODE 6 LOGIT : out_f32[m*N + n] = c + bias[n]
template<int MODE, bool BRAW>
__global__ __launch_bounds__(256) void k_gemm_f32(
    const float* __restrict__ A, long sA,
    const void* __restrict__ Bv, long sB,
    void* __restrict__ Cv,
    const void* __restrict__ bias,
    const float* __restrict__ res,
    int M, int N, int K, float scale, int zoff,
    const int* __restrict__ dflag)
{
  int isbf = BRAW ? dflag[0] : 0;
  int zl = blockIdx.z;       // local slice (A, C)
  int zi = zl + zoff;        // global slice (B, bias) for MODE 0/1
  A += (long)zl * sA;
  __shared__ __align__(16) float As[16][68];
  __shared__ __align__(16) float Bs[16][68];
  int m0 = blockIdx.y * 64, n0 = blockIdx.x * 64;
  int tid = threadIdx.x;
  int tx = tid & 15, ty = tid >> 4;
  int arow = tid >> 2, akc = (tid & 3) * 4;
  int bkr = tid >> 4, bnc = (tid & 15) * 4;
  float c[4][4] = {};
  for (int k0 = 0; k0 < K; k0 += 16){
    float4 av = *(const float4*)&A[(long)(m0 + arow) * K + k0 + akc];
    float4 bv;
    long bidx = (MODE <= 1 ? (long)zi : (long)zl) * sB + (long)(k0 + bkr) * N + n0 + bnc;
    if (BRAW && isbf){
      ushort4 b4 = *(const ushort4*)&((const u16*)Bv)[bidx];
      bv.x = bf2f(b4.x); bv.y = bf2f(b4.y); bv.z = bf2f(b4.z); bv.w = bf2f(b4.w);
    } else {
      bv = *(const float4*)&((const float*)Bv)[bidx];
    }
    __syncthreads();
    As[akc + 0][arow] = av.x; As[akc + 1][arow] = av.y;
    As[akc + 2][arow] = av.z; As[akc + 3][arow] = av.w;
    *(float4*)&Bs[bkr][bnc] = bv;
    __syncthreads();
    #pragma unroll
    for (int k = 0; k < 16; k++){
      float4 a4 = *(const float4*)&As[k][ty * 4];
      float4 b4 = *(const float4*)&Bs[k][tx * 4];
      float aa[4] = {a4.x, a4.y, a4.z, a4.w};
      float bb[4] = {b4.x, b4.y, b4.z, b4.w};
      #pragma unroll
      for (int i = 0; i < 4; i++)
        #pragma unroll
        for (int j = 0; j < 4; j++)
          c[i][j] = fmaf(aa[i], bb[j], c[i][j]);
    }
  }

  if constexpr (MODE == 0){
    float* C = (float*)Cv;
    float bvals[4];
    #pragma unroll
    for (int j = 0; j < 4; j++) bvals[j] = ldf(bias, (long)zi * DD + n0 + tx * 4 + j, isbf);
    #pragma unroll
    for (int i = 0; i < 4; i++){
      int m = m0 + ty * 4 + i;
      long rb = (long)(zl * 8 + (m >> 9)) * ((long)SS * DD) + (long)(m & (SS - 1)) * DD + n0 + tx * 4;
      float4 v = {c[i][0] + bvals[0], c[i][1] + bvals[1], c[i][2] + bvals[2], c[i][3] + bvals[3]};
      *(float4*)&C[rb] = v;
    }
  } else if constexpr (MODE == 1){
    float* C = (float*)Cv;
    int b = m0 >> 9, mr = (m0 & (SS - 1)) + ty * 4;
    #pragma unroll
    for (int j = 0; j < 4; j++){
      int n = n0 + tx * 4 + j;
      float bb2 = ldf(bias, (long)zi * DD + n, isbf);
      long addr = ((long)(zl * 8 + b) * DD + n) * SS + mr;
      float4 v = {c[0][j] + bb2, c[1][j] + bb2, c[2][j] + bb2, c[3][j] + bb2};
      *(float4*)&C[addr] = v;
    }
  } else if constexpr (MODE == 2){
    float* Cz = (float*)Cv + (long)zl * SS * SS;
    #pragma unroll
    for (int i = 0; i < 4; i++){
      long rb = (long)(m0 + ty * 4 + i) * N + n0 + tx * 4;
      float4 v = {c[i][0] * scale, c[i][1] * scale, c[i][2] * scale, c[i][3] * scale};
      *(float4*)&Cz[rb] = v;
    }
  } else if constexpr (MODE == 3){
    float* C = (float*)Cv;
    int b = zl & 7, h = zl >> 3;
    long col0 = (long)(zoff + h) * DD + n0 + tx * 4;
    #pragma unroll
    for (int i = 0; i < 4; i++){
      long rb = ((long)b * SS + m0 + ty * 4 + i) * HD + col0;
      float4 v = {c[i][0], c[i][1], c[i][2], c[i][3]};
      *(float4*)&C[rb] = v;
    }
  } else if constexpr (MODE == 4 || MODE == 5){
    float* C = (float*)Cv;
    float bvals[4];
    #pragma unroll
    for (int j = 0; j < 4; j++) bvals[j] = ldf(bias, n0 + tx * 4 + j, isbf);
    #pragma unroll
    for (int i = 0; i < 4; i++){
      int m = m0 + ty * 4 + i;
      long rb = (long)m * N + n0 + tx * 4;
      float4 v;
      #pragma unroll
      for (int j = 0; j < 4; j++){
        float t = c[i][j] + bvals[j];
        if constexpr (MODE == 4) t = fmaxf(t, 0.f);
        else t += res[rb + j];
        ((float*)&v)[j] = t;
      }
      *(float4*)&C[rb] = v;
    }
  } else {
    // MODE 6: logits, f32 output (reference output dtype is float32)
    float* O = (float*)Cv;
    float bvals[4];
    #pragma unroll
    for (int j = 0; j < 4; j++) bvals[j] = ldf(bias, n0 + tx * 4 + j, isbf);
    #pragma unroll
    for (int i = 0; i < 4; i++){
      int m = m0 + ty * 4 + i;
      float4 v = {c[i][0] + bvals[0], c[i][1] + bvals[1],
                  c[i][2] + bvals[2], c[i][3] + bvals[3]};
      *(float4*)&O[(long)m * N + n0 + tx * 4] = v;
    }
  }
}

// row softmax f32 -> f32, 4 rows (one wave each) per block
__global__ __launch_bounds__(256) void k_softmax(const float* __restrict__ S, float* __restrict__ P)
{
  int row = blockIdx.x * 4 + (threadIdx.x >> 6);
  int lane = threadIdx.x & 63;
  const float* p = S + (long)row * SS + lane * 8;
  float4 v0 = *(const float4*)p;
  float4 v1 = *(const float4*)(p + 4);
  float v[8] = {v0.x, v0.y, v0.z, v0.w, v1.x, v1.y, v1.z, v1.w};
  float mx = v[0];
  #pragma unroll
  for (int i = 1; i < 8; i++) mx = fmaxf(mx, v[i]);
  mx = wave_redmax(mx);
  float e[8], sum = 0.f;
  #pragma unroll
  for (int i = 0; i < 8; i++){ e[i] = expf(v[i] - mx); sum += e[i]; }
  sum = wave_redsum(sum);
  float inv = 1.f / sum;
  float* q = P + (long)row * SS + lane * 8;
  float4 o0 = {e[0] * inv, e[1] * inv, e[2] * inv, e[3] * inv};
  float4 o1 = {e[4] * inv, e[5] * inv, e[6] * inv, e[7] * inv};
  *(float4*)q = o0;
  *(float4*)(q + 4) = o1;
}

// LayerNorm f32 -> f32, one wave per row of 512
__global__ __launch_bounds__(256) void k_ln(
    const float* __restrict__ X, const void* __restrict__ g, const void* __restrict__ be,
    float* __restrict__ Y, const int* __restrict__ dflag)
{
  int isbf = dflag[0];
  int row = blockIdx.x * 4 + (threadIdx.x >> 6);
  int lane = threadIdx.x & 63;
  const float* p = X + (long)row * DD + lane * 8;
  float4 v0 = *(const float4*)p;
  float4 v1 = *(const float4*)(p + 4);
  float v[8] = {v0.x, v0.y, v0.z, v0.w, v1.x, v1.y, v1.z, v1.w};
  float s = 0.f;
  #pragma unroll
  for (int i = 0; i < 8; i++) s += v[i];
  s = wave_redsum(s);
  float mu = s * (1.f / DD);
  float d_[8], sq = 0.f;
  #pragma unroll
  for (int i = 0; i < 8; i++){ d_[i] = v[i] - mu; sq += d_[i] * d_[i]; }
  sq = wave_redsum(sq);
  float rs = 1.f / sqrtf(sq * (1.f / DD) + 1e-5f);
  #pragma unroll
  for (int i = 0; i < 8; i++){
    int dd = lane * 8 + i;
    Y[(long)row * DD + dd] = ldf(g, dd, isbf) * d_[i] * rs + ldf(be, dd, isbf);
  }
}

extern "C" void kernel_launch(void* const* d_in, const int* in_sizes, int n_in,
                              void* d_out, int out_size, void* d_ws, size_t ws_size,
                              hipStream_t stream)
{
  const int* tokens = (const int*)d_in[0];
  const void* emb = d_in[1];
  const void* pe  = d_in[2];
  const void* Wq  = d_in[3];
  const void* bq  = d_in[4];
  const void* Wk  = d_in[5];
  const void* bk  = d_in[6];
  const void* Wv  = d_in[7];
  const void* bv  = d_in[8];
  const void* Wo  = d_in[9];
  const void* bo  = d_in[10];
  const void* g1  = d_in[11];
  const void* be1 = d_in[12];
  const void* W1  = d_in[13];
  const void* b1  = d_in[14];
  const void* W2  = d_in[15];
  const void* b2  = d_in[16];
  const void* g2  = d_in[17];
  const void* be2 = d_in[18];
  const void* Wf  = d_in[19];
  const void* bfb = d_in[20];
  float* out = (float*)d_out;           // reference output dtype = float32
  char* ws = (char*)d_ws;
  char* DO = (char*)d_out;

  const size_t MB = 1ull << 20;
  // ---- d_ws: only dflag + x2 (8.004 MiB) ----
  int*   dflag = (int*)ws;
  float* x2   = (float*)(ws + 4096);

  // ---- d_out as scratch (peak 240 MiB; f32 out buffer is 500 MiB) ----
  float* x    = (float*)(DO + 0 * MB);     // [0,8)    residual 1
  float* xm   = (float*)(DO + 8 * MB);     // [8,16)   masked x -> proj
  float* cat  = (float*)(DO + 16 * MB);    // [16,80)  o in torch.cat order (f32)
  float* qb   = (float*)(DO + 80 * MB);    // [80,112)  q (group)   -> x1f [80,88)
  float* kT   = (float*)(DO + 112 * MB);   // [112,144) kT (group)  -> ff1 [88,120)
  float* vb   = (float*)(DO + 144 * MB);   // [144,176) v (group)
  float* sc   = (float*)(DO + 176 * MB);   // [176,208) scores (group)
  float* at   = (float*)(DO + 208 * MB);   // [208,240) attn f32 (group)
  float* proj = (float*)(DO + 8 * MB);
  float* x1f  = (float*)(DO + 80 * MB);
  float* ff1  = (float*)(DO + 88 * MB);    // [88,120) f32 [4096][2048]
  float* ff2  = (float*)(DO + 120 * MB);   // [120,128)

  const float scale = 0.04419417382415922f;  // 1/sqrt(512)
  const long HSL = 262144;  // 512*512 elements per head-slice

  k_dflag<<<1, 1, 0, stream>>>(pe, dflag);
  k_embed<<<dim3(4096), 256, 0, stream>>>(tokens, emb, pe, x, xm, dflag);

  // attention, two head-groups of 4
  for (int g = 0; g < 2; g++){
    int zoff = g * 4;
    k_gemm_f32<0, true><<<dim3(8, 64, 4), 256, 0, stream>>>(
        xm, 0, Wq, HSL, qb, bq, nullptr, MTOT, DD, DD, 0.f, zoff, dflag);
    k_gemm_f32<1, true><<<dim3(8, 64, 4), 256, 0, stream>>>(
        xm, 0, Wk, HSL, kT, bk, nullptr, MTOT, DD, DD, 0.f, zoff, dflag);
    k_gemm_f32<0, true><<<dim3(8, 64, 4), 256, 0, stream>>>(
        xm, 0, Wv, HSL, vb, bv, nullptr, MTOT, DD, DD, 0.f, zoff, dflag);

    k_gemm_f32<2, false><<<dim3(8, 8, 32), 256, 0, stream>>>(
        qb, HSL, kT, HSL, sc, nullptr, nullptr, SS, SS, DD, scale, 0, dflag);
    k_softmax<<<dim3(4096), 256, 0, stream>>>(sc, at);
    k_gemm_f32<3, false><<<dim3(8, 8, 32), 256, 0, stream>>>(
        at, HSL, vb, HSL, cat, nullptr, nullptr, SS, DD, SS, 0.f, zoff, dflag);
  }

  // proj = cat @ Wo + bo + x
  k_gemm_f32<5, true><<<dim3(8, 64, 1), 256, 0, stream>>>(
      cat, 0, Wo, 0, proj, bo, x, MTOT, DD, HD, 0.f, 0, dflag);
  k_ln<<<dim3(1024), 256, 0, stream>>>(proj, g1, be1, x1f, dflag);

  // ff = relu(x1 @ W1 + b1) @ W2 + b2 + x1
  k_gemm_f32<4, true><<<dim3(32, 64, 1), 256, 0, stream>>>(
      x1f, 0, W1, 0, ff1, b1, nullptr, MTOT, NFF, DD, 0.f, 0, dflag);
  k_gemm_f32<5, true><<<dim3(8, 64, 1), 256, 0, stream>>>(
      ff1, 0, W2, 0, ff2, b2, x1f, MTOT, DD, NFF, 0.f, 0, dflag);
  k_ln<<<dim3(1024), 256, 0, stream>>>(ff2, g2, be2, x2, dflag);

  // logits = x2 @ Wf + bf -> f32 out (reads only ws + inputs; writes all d_out)
  k_gemm_f32<6, true><<<dim3(500, 64, 1), 256, 0, stream>>>(
      x2, 0, Wf, 0, out, bfb, nullptr, MTOT, VV, DD, 0.f, 0, dflag);
}

// Round 6
// 1621.987 us; speedup vs baseline: 2.1799x; 2.1799x over previous
//
#include <hip/hip_runtime.h>

typedef unsigned short u16;
typedef unsigned int u32;
typedef short s16x8 __attribute__((ext_vector_type(8)));
typedef __bf16 bf16x8 __attribute__((ext_vector_type(8)));
typedef float f32x4 __attribute__((ext_vector_type(4)));

#define DEVI static __device__ __forceinline__

#define SS 512
#define DD 512
#define NFF 2048
#define VV 32000
#define MTOT 4096
#define HD 4096

DEVI float bf2f(u16 h){ return __uint_as_float(((u32)h) << 16); }
DEVI u16 f2bf(float f){
  u32 u = __float_as_uint(f);
  return (u16)((u + 0x7FFFu + ((u >> 16) & 1u)) >> 16);
}
DEVI float ldf(const void* p, long i, int isbf){
  return isbf ? bf2f(((const u16*)p)[i]) : ((const float*)p)[i];
}

DEVI f32x4 mfma16(s16x8 a, s16x8 b, f32x4 c){
  return __builtin_amdgcn_mfma_f32_16x16x32_bf16(
      __builtin_bit_cast(bf16x8, a), __builtin_bit_cast(bf16x8, b), c, 0, 0, 0);
}

DEVI float wave_redmax(float v){
  #pragma unroll
  for (int off = 32; off > 0; off >>= 1) v = fmaxf(v, __shfl_xor(v, off, 64));
  return v;
}
DEVI float wave_redsum(float v){
  #pragma unroll
  for (int off = 32; off > 0; off >>= 1) v += __shfl_xor(v, off, 64);
  return v;
}

// pe row0 = [sin0=0, cos0=1, ...]: first u32 word = 0x3F800000 if bf16, 0x00000000 if f32
__global__ void k_dflag(const void* pe, int* flag){
  flag[0] = (*(const u32*)pe == 0x3F800000u) ? 1 : 0;
}

__global__ __launch_bounds__(256) void k_embed(
    const int* __restrict__ tok, const void* __restrict__ emb, const void* __restrict__ pe,
    float* __restrict__ x, float* __restrict__ xm, u16* __restrict__ xmb,
    const int* __restrict__ dflag)
{
  int isbf = dflag[0];
  int blk = blockIdx.x;
  int s = blk & (SS - 1);
  int t = tok[blk];
  long base = (long)blk * DD;
  for (int d = threadIdx.x; d < DD; d += 256){
    float e = ldf(emb, (long)t * DD + d, isbf) + ldf(pe, (long)s * DD + d, isbf);
    x[base + d] = e;
    float v = (d <= s) ? e : 0.f;   // triu(ones(S,D),k=1) zeroes d > s
    xm[base + d] = v;
    xmb[base + d] = f2bf(v);
  }
}

// f32 NN GEMM (argmax-critical path only): C = A[M,K] @ B[K,N].
// MODE 0 QPROJ : C[(zl*8+b)*S*D + s*D + n] = c + bias[zi*D+n]
// MODE 1 KPROJ : C[((zl*8+b)*D + n)*S + s] = c + bias[zi*D+n]
// MODE 2 SCORE : C[zl*S*S + s*S + t] = c * scale
template<int MODE, bool BRAW>
__global__ __launch_bounds__(256) void k_gemm_f32(
    const float* __restrict__ A, long sA,
    const void* __restrict__ Bv, long sB,
    float* __restrict__ C,
    const void* __restrict__ bias,
    int M, int N, int K, float scale, int zoff,
    const int* __restrict__ dflag)
{
  int isbf = BRAW ? dflag[0] : 0;
  int zl = blockIdx.z;
  int zi = zl + zoff;
  A += (long)zl * sA;
  __shared__ __align__(16) float As[16][68];
  __shared__ __align__(16) float Bs[16][68];
  int m0 = blockIdx.y * 64, n0 = blockIdx.x * 64;
  int tid = threadIdx.x;
  int tx = tid & 15, ty = tid >> 4;
  int arow = tid >> 2, akc = (tid & 3) * 4;
  int bkr = tid >> 4, bnc = (tid & 15) * 4;
  float c[4][4] = {};
  for (int k0 = 0; k0 < K; k0 += 16){
    float4 av = *(const float4*)&A[(long)(m0 + arow) * K + k0 + akc];
    float4 bv;
    long bidx = (MODE <= 1 ? (long)zi : (long)zl) * sB + (long)(k0 + bkr) * N + n0 + bnc;
    if (BRAW && isbf){
      ushort4 b4 = *(const ushort4*)&((const u16*)Bv)[bidx];
      bv.x = bf2f(b4.x); bv.y = bf2f(b4.y); bv.z = bf2f(b4.z); bv.w = bf2f(b4.w);
    } else {
      bv = *(const float4*)&((const float*)Bv)[bidx];
    }
    __syncthreads();
    As[akc + 0][arow] = av.x; As[akc + 1][arow] = av.y;
    As[akc + 2][arow] = av.z; As[akc + 3][arow] = av.w;
    *(float4*)&Bs[bkr][bnc] = bv;
    __syncthreads();
    #pragma unroll
    for (int k = 0; k < 16; k++){
      float4 a4 = *(const float4*)&As[k][ty * 4];
      float4 b4 = *(const float4*)&Bs[k][tx * 4];
      float aa[4] = {a4.x, a4.y, a4.z, a4.w};
      float bb[4] = {b4.x, b4.y, b4.z, b4.w};
      #pragma unroll
      for (int i = 0; i < 4; i++)
        #pragma unroll
        for (int j = 0; j < 4; j++)
          c[i][j] = fmaf(aa[i], bb[j], c[i][j]);
    }
  }
  if constexpr (MODE == 0){
    float bvals[4];
    #pragma unroll
    for (int j = 0; j < 4; j++) bvals[j] = ldf(bias, (long)zi * DD + n0 + tx * 4 + j, isbf);
    #pragma unroll
    for (int i = 0; i < 4; i++){
      int m = m0 + ty * 4 + i;
      long rb = (long)(zl * 8 + (m >> 9)) * ((long)SS * DD) + (long)(m & (SS - 1)) * DD + n0 + tx * 4;
      float4 v = {c[i][0] + bvals[0], c[i][1] + bvals[1], c[i][2] + bvals[2], c[i][3] + bvals[3]};
      *(float4*)&C[rb] = v;
    }
  } else if constexpr (MODE == 1){
    int b = m0 >> 9, mr = (m0 & (SS - 1)) + ty * 4;
    #pragma unroll
    for (int j = 0; j < 4; j++){
      int n = n0 + tx * 4 + j;
      float bb2 = ldf(bias, (long)zi * DD + n, isbf);
      long addr = ((long)(zl * 8 + b) * DD + n) * SS + mr;
      float4 v = {c[0][j] + bb2, c[1][j] + bb2, c[2][j] + bb2, c[3][j] + bb2};
      *(float4*)&C[addr] = v;
    }
  } else {
    float* Cz = C + (long)zl * SS * SS;
    #pragma unroll
    for (int i = 0; i < 4; i++){
      long rb = (long)(m0 + ty * 4 + i) * N + n0 + tx * 4;
      float4 v = {c[i][0] * scale, c[i][1] * scale, c[i][2] * scale, c[i][3] * scale};
      *(float4*)&Cz[rb] = v;
    }
  }
}

enum { EP_VT = 0, EP_CAT = 1, EP_F32RES = 2, EP_RELU = 3, EP_OUT = 4 };

// bf16 MFMA GEMM, 128x128 tile, BK=32, 4 waves (2x2 of 64x64), 16x16x32.
// A: bf16 [M][K] (+z*sA). B: BTRP ? bf16 [N][K] (+z*sB) : raw [K][N] f32/bf16 per dflag.
// GSWAP swaps grid x/y roles (m-tiles fastest for B-operand L2 reuse).
template<int MODE, bool BTRP, bool GSWAP>
__global__ __launch_bounds__(256) void k_mfma(
    const u16* __restrict__ A, long sA,
    const void* __restrict__ Bv, long sB,
    void* __restrict__ Cv,
    const void* __restrict__ bias,
    const float* __restrict__ res,
    int N, int K, int ldc,
    const int* __restrict__ dflag)
{
  int isbf = dflag[0];
  int z = blockIdx.z;
  const u16* Ab = A + (long)z * sA;
  __shared__ __align__(16) u16 As[4][128][8];
  __shared__ __align__(16) u16 Bs[4][128][8];
  int m0 = (GSWAP ? blockIdx.x : blockIdx.y) * 128;
  int n0 = (GSWAP ? blockIdx.y : blockIdx.x) * 128;
  int tid = threadIdx.x;
  int lane = tid & 63, w = tid >> 6;
  int wr = (w >> 1) * 64, wc = (w & 1) * 64;
  int l15 = lane & 15, l4 = lane >> 4;
  f32x4 zero = {0.f, 0.f, 0.f, 0.f};
  f32x4 acc[4][4];
  #pragma unroll
  for (int i = 0; i < 4; i++)
    #pragma unroll
    for (int j = 0; j < 4; j++) acc[i][j] = zero;

  int srow = tid >> 2, skc = tid & 3;   // A (and TRP-B) staging
  int bcol = tid & 127, bkq = tid >> 7; // RAW-B staging: column, k-quarter

  for (int k0 = 0; k0 < K; k0 += 32){
    uint4 a0 = *(const uint4*)&Ab[(long)(m0 + srow) * K + k0 + skc * 8];
    uint4 a1 = *(const uint4*)&Ab[(long)(m0 + srow + 64) * K + k0 + skc * 8];
    uint4 b0, b1;
    u16 braw[16];
    if constexpr (BTRP){
      const u16* Bt = (const u16*)Bv + (long)z * sB;
      b0 = *(const uint4*)&Bt[(long)(n0 + srow) * K + k0 + skc * 8];
      b1 = *(const uint4*)&Bt[(long)(n0 + srow + 64) * K + k0 + skc * 8];
    } else {
      long nb = n0 + bcol;
      if (isbf){
        const u16* Bh = (const u16*)Bv + (long)z * sB;
        #pragma unroll
        for (int j = 0; j < 16; j++) braw[j] = Bh[(long)(k0 + bkq * 16 + j) * N + nb];
      } else {
        const float* Bf = (const float*)Bv + (long)z * sB;
        #pragma unroll
        for (int j = 0; j < 16; j++) braw[j] = f2bf(Bf[(long)(k0 + bkq * 16 + j) * N + nb]);
      }
    }
    __syncthreads();
    *(uint4*)&As[skc][srow][0] = a0;
    *(uint4*)&As[skc][srow + 64][0] = a1;
    if constexpr (BTRP){
      *(uint4*)&Bs[skc][srow][0] = b0;
      *(uint4*)&Bs[skc][srow + 64][0] = b1;
    } else {
      #pragma unroll
      for (int jj = 0; jj < 4; jj++){
        int kk = bkq * 16 + jj * 4;  // k-offset within BK: {0,4,8,12} or {16,20,24,28}
        uint2 pk;
        pk.x = (u32)braw[jj * 4 + 0] | ((u32)braw[jj * 4 + 1] << 16);
        pk.y = (u32)braw[jj * 4 + 2] | ((u32)braw[jj * 4 + 3] << 16);
        *(uint2*)&Bs[kk >> 3][bcol][kk & 7] = pk;
      }
    }
    __syncthreads();
    s16x8 af[4], bfr[4];
    #pragma unroll
    for (int i = 0; i < 4; i++) af[i] = *(const s16x8*)&As[l4][wr + i * 16 + l15][0];
    #pragma unroll
    for (int j = 0; j < 4; j++) bfr[j] = *(const s16x8*)&Bs[l4][wc + j * 16 + l15][0];
    #pragma unroll
    for (int i = 0; i < 4; i++)
      #pragma unroll
      for (int j = 0; j < 4; j++)
        acc[i][j] = mfma16(af[i], bfr[j], acc[i][j]);
  }

  int mbase = m0 + wr + l4 * 4;   // C row = mbase + i*16 + r
  int nbase = n0 + wc + l15;      // C col = nbase + j*16
  if constexpr (MODE == EP_VT){
    // vT[(z*8 + b)][d = n][s] = c + bv[z*D + n]; 4 regs = 4 consecutive s
    u16* C = (u16*)Cv;
    #pragma unroll
    for (int i = 0; i < 4; i++){
      int mrow = mbase + i * 16;
      int b = mrow >> 9, s = mrow & (SS - 1);
      #pragma unroll
      for (int j = 0; j < 4; j++){
        int n = nbase + j * 16;
        float badd = ldf(bias, (long)z * DD + n, isbf);
        ushort4 pk;
        pk.x = f2bf(acc[i][j][0] + badd); pk.y = f2bf(acc[i][j][1] + badd);
        pk.z = f2bf(acc[i][j][2] + badd); pk.w = f2bf(acc[i][j][3] + badd);
        *(ushort4*)&C[((long)(z * 8 + b) * DD + n) * SS + s] = pk;
      }
    }
  } else if constexpr (MODE == EP_CAT){
    // cat[(b*S + s)][h*D + n] = c ; z = h*8+b
    u16* C = (u16*)Cv;
    int h = z >> 3, b = z & 7;
    #pragma unroll
    for (int i = 0; i < 4; i++){
      int s = mbase + i * 16;
      #pragma unroll
      for (int j = 0; j < 4; j++){
        int n = nbase + j * 16;
        #pragma unroll
        for (int r = 0; r < 4; r++)
          C[((long)b * SS + s + r) * HD + (long)h * DD + n] = f2bf(acc[i][j][r]);
      }
    }
  } else if constexpr (MODE == EP_F32RES){
    float* C = (float*)Cv;
    #pragma unroll
    for (int j = 0; j < 4; j++){
      int n = nbase + j * 16;
      float badd = ldf(bias, n, isbf);
      #pragma unroll
      for (int i = 0; i < 4; i++)
        #pragma unroll
        for (int r = 0; r < 4; r++){
          long a = (long)(mbase + i * 16 + r) * ldc + n;
          C[a] = acc[i][j][r] + badd + res[a];
        }
    }
  } else if constexpr (MODE == EP_RELU){
    u16* C = (u16*)Cv;
    #pragma unroll
    for (int j = 0; j < 4; j++){
      int n = nbase + j * 16;
      float badd = ldf(bias, n, isbf);
      #pragma unroll
      for (int i = 0; i < 4; i++)
        #pragma unroll
        for (int r = 0; r < 4; r++)
          C[(long)(mbase + i * 16 + r) * ldc + n] = f2bf(fmaxf(acc[i][j][r] + badd, 0.f));
    }
  } else {
    float* O = (float*)Cv;
    #pragma unroll
    for (int j = 0; j < 4; j++){
      int n = nbase + j * 16;
      float badd = ldf(bias, n, isbf);
      #pragma unroll
      for (int i = 0; i < 4; i++)
        #pragma unroll
        for (int r = 0; r < 4; r++)
          O[(long)(mbase + i * 16 + r) * ldc + n] = acc[i][j][r] + badd;
    }
  }
}

// row softmax f32 -> bf16, 4 rows (one wave each) per block
__global__ __launch_bounds__(256) void k_softmax(const float* __restrict__ S, u16* __restrict__ P)
{
  int row = blockIdx.x * 4 + (threadIdx.x >> 6);
  int lane = threadIdx.x & 63;
  const float* p = S + (long)row * SS + lane * 8;
  float4 v0 = *(const float4*)p;
  float4 v1 = *(const float4*)(p + 4);
  float v[8] = {v0.x, v0.y, v0.z, v0.w, v1.x, v1.y, v1.z, v1.w};
  float mx = v[0];
  #pragma unroll
  for (int i = 1; i < 8; i++) mx = fmaxf(mx, v[i]);
  mx = wave_redmax(mx);
  float e[8], sum = 0.f;
  #pragma unroll
  for (int i = 0; i < 8; i++){ e[i] = expf(v[i] - mx); sum += e[i]; }
  sum = wave_redsum(sum);
  float inv = 1.f / sum;
  u16* q = P + (long)row * SS + lane * 8;
  ushort4 o0, o1;
  o0.x = f2bf(e[0] * inv); o0.y = f2bf(e[1] * inv);
  o0.z = f2bf(e[2] * inv); o0.w = f2bf(e[3] * inv);
  o1.x = f2bf(e[4] * inv); o1.y = f2bf(e[5] * inv);
  o1.z = f2bf(e[6] * inv); o1.w = f2bf(e[7] * inv);
  *(ushort4*)q = o0;
  *(ushort4*)(q + 4) = o1;
}

// LayerNorm f32 -> bf16 (+ optional f32), one wave per row of 512
template<bool WF32>
__global__ __launch_bounds__(256) void k_ln(
    const float* __restrict__ X, const void* __restrict__ g, const void* __restrict__ be,
    u16* __restrict__ Yb, float* __restrict__ Yf, const int* __restrict__ dflag)
{
  int isbf = dflag[0];
  int row = blockIdx.x * 4 + (threadIdx.x >> 6);
  int lane = threadIdx.x & 63;
  const float* p = X + (long)row * DD + lane * 8;
  float4 v0 = *(const float4*)p;
  float4 v1 = *(const float4*)(p + 4);
  float v[8] = {v0.x, v0.y, v0.z, v0.w, v1.x, v1.y, v1.z, v1.w};
  float s = 0.f;
  #pragma unroll
  for (int i = 0; i < 8; i++) s += v[i];
  s = wave_redsum(s);
  float mu = s * (1.f / DD);
  float d_[8], sq = 0.f;
  #pragma unroll
  for (int i = 0; i < 8; i++){ d_[i] = v[i] - mu; sq += d_[i] * d_[i]; }
  sq = wave_redsum(sq);
  float rs = 1.f / sqrtf(sq * (1.f / DD) + 1e-5f);
  #pragma unroll
  for (int i = 0; i < 8; i++){
    int dd = lane * 8 + i;
    float y = ldf(g, dd, isbf) * d_[i] * rs + ldf(be, dd, isbf);
    Yb[(long)row * DD + dd] = f2bf(y);
    if (WF32) Yf[(long)row * DD + dd] = y;
  }
}

extern "C" void kernel_launch(void* const* d_in, const int* in_sizes, int n_in,
                              void* d_out, int out_size, void* d_ws, size_t ws_size,
                              hipStream_t stream)
{
  const int* tokens = (const int*)d_in[0];
  const void* emb = d_in[1];
  const void* pe  = d_in[2];
  const void* Wq  = d_in[3];
  const void* bq  = d_in[4];
  const void* Wk  = d_in[5];
  const void* bk  = d_in[6];
  const void* Wv  = d_in[7];
  const void* bv  = d_in[8];
  const void* Wo  = d_in[9];
  const void* bo  = d_in[10];
  const void* g1  = d_in[11];
  const void* be1 = d_in[12];
  const void* W1  = d_in[13];
  const void* b1  = d_in[14];
  const void* W2  = d_in[15];
  const void* b2  = d_in[16];
  const void* g2  = d_in[17];
  const void* be2 = d_in[18];
  const void* Wf  = d_in[19];
  const void* bfb = d_in[20];
  float* out = (float*)d_out;   // reference output dtype = float32
  char* ws = (char*)d_ws;
  char* DO = (char*)d_out;

  const size_t MB = 1ull << 20;
  // ---- d_ws: dflag + x2 bf16 (~4.01 MiB; 8 MiB proven safe in round 5) ----
  int* dflag = (int*)ws;
  u16* x2b   = (u16*)(ws + 4096);

  // ---- d_out as scratch (peak 248 of 500 MiB) ----
  float* x    = (float*)(DO + 0 * MB);     // residual 1
  float* xm   = (float*)(DO + 8 * MB);     // masked x f32 -> proj f32
  u16*   xmb  = (u16*)(DO + 16 * MB);      // masked x bf16
  u16*   attn = (u16*)(DO + 20 * MB);      // [64 hb][S][S] bf16 (both groups)
  u16*   vT   = (u16*)(DO + 52 * MB);      // [64 hb][D][S] bf16
  u16*   cat  = (u16*)(DO + 84 * MB);      // [4096][4096] bf16
  float* qb   = (float*)(DO + 116 * MB);   // q f32 (group of 4 heads)
  float* kT   = (float*)(DO + 148 * MB);   // kT f32 (group)
  float* sc   = (float*)(DO + 180 * MB);   // scores f32 (group)
  float* x1f  = (float*)(DO + 212 * MB);
  u16*   x1b  = (u16*)(DO + 220 * MB);
  u16*   ff1  = (u16*)(DO + 224 * MB);     // [4096][2048] bf16
  float* ff2  = (float*)(DO + 240 * MB);
  float* proj = (float*)(DO + 8 * MB);

  const float scale = 0.04419417382415922f;  // 1/sqrt(512)
  const long HSL = 262144;  // 512*512

  k_dflag<<<1, 1, 0, stream>>>(pe, dflag);
  k_embed<<<dim3(4096), 256, 0, stream>>>(tokens, emb, pe, x, xm, xmb, dflag);

  // ---- f32 argmax-critical path: q, k, scores, softmax (two head-groups of 4) ----
  for (int g = 0; g < 2; g++){
    int zoff = g * 4;
    k_gemm_f32<0, true><<<dim3(8, 64, 4), 256, 0, stream>>>(
        xm, 0, Wq, HSL, qb, bq, MTOT, DD, DD, 0.f, zoff, dflag);
    k_gemm_f32<1, true><<<dim3(8, 64, 4), 256, 0, stream>>>(
        xm, 0, Wk, HSL, kT, bk, MTOT, DD, DD, 0.f, zoff, dflag);
    k_gemm_f32<2, false><<<dim3(8, 8, 32), 256, 0, stream>>>(
        qb, HSL, kT, HSL, sc, nullptr, SS, SS, DD, scale, 0, dflag);
    k_softmax<<<dim3(4096), 256, 0, stream>>>(sc, attn + (long)g * 32 * HSL);
  }

  // ---- bf16 MFMA path ----
  // v = xm @ Wv + bv, written transposed per (h,b)
  k_mfma<EP_VT, false, false><<<dim3(4, 32, 8), 256, 0, stream>>>(
      xmb, 0, Wv, HSL, vT, bv, nullptr, DD, DD, 0, dflag);
  // o = attn @ v  -> cat
  k_mfma<EP_CAT, true, false><<<dim3(4, 4, 64), 256, 0, stream>>>(
      attn, HSL, vT, HSL, cat, nullptr, nullptr, DD, SS, 0, dflag);
  // proj = cat @ Wo + bo + x
  k_mfma<EP_F32RES, false, false><<<dim3(4, 32, 1), 256, 0, stream>>>(
      cat, 0, Wo, 0, proj, bo, x, DD, HD, DD, dflag);
  k_ln<true><<<dim3(1024), 256, 0, stream>>>(proj, g1, be1, x1b, x1f, dflag);
  // ff1 = relu(x1 @ W1 + b1)
  k_mfma<EP_RELU, false, false><<<dim3(16, 32, 1), 256, 0, stream>>>(
      x1b, 0, W1, 0, ff1, b1, nullptr, NFF, DD, NFF, dflag);
  // ff2 = ff1 @ W2 + b2 + x1
  k_mfma<EP_F32RES, false, false><<<dim3(4, 32, 1), 256, 0, stream>>>(
      ff1, 0, W2, 0, ff2, b2, x1f, DD, NFF, DD, dflag);
  k_ln<false><<<dim3(1024), 256, 0, stream>>>(ff2, g2, be2, x2b, nullptr, dflag);
  // logits = x2 @ Wf + bf -> f32 out (reads only ws + raw inputs; GSWAP for Wf L2 reuse)
  k_mfma<EP_OUT, false, true><<<dim3(32, 250, 1), 256, 0, stream>>>(
      x2b, 0, Wf, 0, out, bfb, nullptr, VV, DD, VV, dflag);
}

// Round 7
// 1348.686 us; speedup vs baseline: 2.6216x; 1.2026x over previous
//
#include <hip/hip_runtime.h>

typedef unsigned short u16;
typedef unsigned int u32;
typedef short s16x8 __attribute__((ext_vector_type(8)));
typedef __bf16 bf16x8 __attribute__((ext_vector_type(8)));
typedef float f32x4 __attribute__((ext_vector_type(4)));

#define DEVI static __device__ __forceinline__

#define SS 512
#define DD 512
#define NFF 2048
#define VV 32000
#define MTOT 4096
#define HD 4096
#define KC 1536   // split-concat K

DEVI float bf2f(u16 h){ return __uint_as_float(((u32)h) << 16); }
DEVI u16 f2bf(float f){
  u32 u = __float_as_uint(f);
  return (u16)((u + 0x7FFFu + ((u >> 16) & 1u)) >> 16);
}
DEVI float ldf(const void* p, long i, int isbf){
  return isbf ? bf2f(((const u16*)p)[i]) : ((const float*)p)[i];
}

DEVI f32x4 mfma16(s16x8 a, s16x8 b, f32x4 c){
  return __builtin_amdgcn_mfma_f32_16x16x32_bf16(
      __builtin_bit_cast(bf16x8, a), __builtin_bit_cast(bf16x8, b), c, 0, 0, 0);
}

// direct global->LDS 16B copy; dst is wave-uniform base + lane*16, src per-lane
typedef const __attribute__((address_space(1))) unsigned int* gup;
typedef __attribute__((address_space(3))) unsigned int* lup;
DEVI void gload16(const void* g, void* l){
  __builtin_amdgcn_global_load_lds((gup)g, (lup)l, 16, 0, 0);
}

DEVI float wave_redmax(float v){
  #pragma unroll
  for (int off = 32; off > 0; off >>= 1) v = fmaxf(v, __shfl_xor(v, off, 64));
  return v;
}
DEVI float wave_redsum(float v){
  #pragma unroll
  for (int off = 32; off > 0; off >>= 1) v += __shfl_xor(v, off, 64);
  return v;
}

// pe row0 = [sin0=0, cos0=1, ...]: first u32 word = 0x3F800000 if bf16, 0x00000000 if f32
__global__ void k_dflag(const void* pe, int* flag){
  flag[0] = (*(const u32*)pe == 0x3F800000u) ? 1 : 0;
}

// embed + residual + masked split-concat: xm_cat[m][0:512]=hi, [512:1024]=hi, [1024:1536]=lo
__global__ __launch_bounds__(256) void k_embed(
    const int* __restrict__ tok, const void* __restrict__ emb, const void* __restrict__ pe,
    float* __restrict__ x, u16* __restrict__ xm_cat, const int* __restrict__ dflag)
{
  int isbf = dflag[0];
  int blk = blockIdx.x;
  int s = blk & (SS - 1);
  int t = tok[blk];
  long rb = (long)blk * KC;
  for (int d = threadIdx.x; d < DD; d += 256){
    float e = ldf(emb, (long)t * DD + d, isbf) + ldf(pe, (long)s * DD + d, isbf);
    x[(long)blk * DD + d] = e;
    float m = (d <= s) ? e : 0.f;           // triu(ones(S,D),k=1) zeroes d > s
    u16 hi = f2bf(m);
    u16 lo = f2bf(m - bf2f(hi));
    xm_cat[rb + d] = hi;
    xm_cat[rb + 512 + d] = hi;
    xm_cat[rb + 1024 + d] = lo;
  }
}

// split-transpose for Wq/Wk: in W[z][512 d][512 e] f32 -> out[z][512 e][1536]:
// band0[e][d]=hi, band1[e][d]=lo, band2[e][d]=hi   (matches A=[xh|xh|xl])
__global__ __launch_bounds__(256) void k_wsplitT(
    const void* __restrict__ in, u16* __restrict__ out, const int* __restrict__ dflag)
{
  int isbf = dflag[0];
  long zin = (long)blockIdx.z * DD * DD;
  long zout = (long)blockIdx.z * DD * KC;
  __shared__ float t[32][33];
  int e0 = blockIdx.x * 32, d0 = blockIdx.y * 32;
  int tx = threadIdx.x & 31, ty = threadIdx.x >> 5;
  #pragma unroll
  for (int i = 0; i < 4; i++){
    int d = ty + i * 8;
    t[d][tx] = ldf(in, zin + (long)(d0 + d) * DD + e0 + tx, isbf);
  }
  __syncthreads();
  #pragma unroll
  for (int i = 0; i < 4; i++){
    int e = ty + i * 8;
    float v = t[tx][e];
    u16 hi = f2bf(v);
    u16 lo = f2bf(v - bf2f(hi));
    long ob = zout + (long)(e0 + e) * KC + d0 + tx;
    out[ob] = hi;
    out[ob + 512] = lo;
    out[ob + 1024] = hi;
  }
}

// plain transpose f32/bf16 -> bf16: in [R][C] (+z*R*C) -> out [C][R] (+z*R*C)
__global__ __launch_bounds__(256) void k_transT(
    const void* __restrict__ in, u16* __restrict__ out, int R, int C,
    const int* __restrict__ dflag)
{
  int isbf = dflag[0];
  long zo = (long)blockIdx.z * R * C;
  __shared__ float t[32][33];
  int c0 = blockIdx.x * 32, r0 = blockIdx.y * 32;
  int tx = threadIdx.x & 31, ty = threadIdx.x >> 5;
  #pragma unroll
  for (int i = 0; i < 4; i++){
    int r = ty + i * 8;
    t[r][tx] = ldf(in, zo + (long)(r0 + r) * C + c0 + tx, isbf);
  }
  __syncthreads();
  #pragma unroll
  for (int i = 0; i < 4; i++){
    int c = ty + i * 8;
    out[zo + (long)(c0 + c) * R + r0 + tx] = f2bf(t[tx][c]);
  }
}

enum { EP_QCAT = 0, EP_KCAT = 1, EP_SCALE = 2, EP_VT = 3, EP_CAT = 4,
       EP_F32RES = 5, EP_RELU = 6, EP_OUT = 7 };

// bf16 MFMA GEMM: C = A[.][K](lda) @ Bt[N][K]^T. 128x128 tile, BK=32, 4 waves,
// 16x16x32 MFMA, global_load_lds staging (width 16).
template<int MODE, bool GSWAP>
__global__ __launch_bounds__(256) void k_mfma(
    const u16* __restrict__ A, long sA, int lda,
    const u16* __restrict__ Bt, long sB,
    void* __restrict__ Cv,
    const void* __restrict__ bias,
    const float* __restrict__ res,
    int K, int ldc, float scale,
    const int* __restrict__ dflag)
{
  int isbf = dflag[0];
  int z = blockIdx.z;
  const u16* Ab = A + (long)z * sA;
  const u16* Bb = Bt + (long)z * sB;
  __shared__ __align__(16) u16 As[4][128][8];   // slot (skc*128+srow) <-> byte slot*16
  __shared__ __align__(16) u16 Bs[4][128][8];
  int m0 = (GSWAP ? blockIdx.x : blockIdx.y) * 128;
  int n0 = (GSWAP ? blockIdx.y : blockIdx.x) * 128;
  int tid = threadIdx.x;
  int lane = tid & 63, w = tid >> 6;
  int wr = (w >> 1) * 64, wc = (w & 1) * 64;
  int l15 = lane & 15, l4 = lane >> 4;
  u16* AsF = &As[0][0][0];
  u16* BsF = &Bs[0][0][0];
  int s0 = w * 64 + lane;          // slots 0..255
  int ar0 = s0 & 127, ak0 = s0 >> 7;     // skc 0..1
  int ar1 = ar0, ak1 = ak0 + 2;          // slots 256..511: same row, skc 2..3
  f32x4 zero = {0.f, 0.f, 0.f, 0.f};
  f32x4 acc[4][4];
  #pragma unroll
  for (int i = 0; i < 4; i++)
    #pragma unroll
    for (int j = 0; j < 4; j++) acc[i][j] = zero;

  for (int k0 = 0; k0 < K; k0 += 32){
    __syncthreads();   // previous iteration's ds_reads done before overwrite
    gload16(Ab + (long)(m0 + ar0) * lda + k0 + ak0 * 8, AsF + (long)(w * 64) * 8);
    gload16(Ab + (long)(m0 + ar1) * lda + k0 + ak1 * 8, AsF + (long)(256 + w * 64) * 8);
    gload16(Bb + (long)(n0 + ar0) * K + k0 + ak0 * 8, BsF + (long)(w * 64) * 8);
    gload16(Bb + (long)(n0 + ar1) * K + k0 + ak1 * 8, BsF + (long)(256 + w * 64) * 8);
    __syncthreads();   // compiler drains vmcnt before barrier -> data ready
    s16x8 af[4], bfr[4];
    #pragma unroll
    for (int i = 0; i < 4; i++) af[i] = *(const s16x8*)&As[l4][wr + i * 16 + l15][0];
    #pragma unroll
    for (int j = 0; j < 4; j++) bfr[j] = *(const s16x8*)&Bs[l4][wc + j * 16 + l15][0];
    #pragma unroll
    for (int i = 0; i < 4; i++)
      #pragma unroll
      for (int j = 0; j < 4; j++)
        acc[i][j] = mfma16(af[i], bfr[j], acc[i][j]);
  }

  int mbase = m0 + wr + l4 * 4;   // C row = mbase + i*16 + r
  int nbase = n0 + wc + l15;      // C col = nbase + j*16
  if constexpr (MODE == EP_QCAT || MODE == EP_KCAT){
    u16* C = (u16*)Cv + (long)z * ((long)MTOT * KC);
    #pragma unroll
    for (int j = 0; j < 4; j++){
      int n = nbase + j * 16;
      float badd = ldf(bias, (long)z * DD + n, isbf);
      #pragma unroll
      for (int i = 0; i < 4; i++)
        #pragma unroll
        for (int r = 0; r < 4; r++){
          float qv = acc[i][j][r] + badd;
          u16 hi = f2bf(qv);
          u16 lo = f2bf(qv - bf2f(hi));
          long rb = (long)(mbase + i * 16 + r) * KC;
          C[rb + n] = hi;
          if constexpr (MODE == EP_QCAT){ C[rb + 512 + n] = hi; C[rb + 1024 + n] = lo; }
          else                          { C[rb + 512 + n] = lo; C[rb + 1024 + n] = hi; }
        }
    }
  } else if constexpr (MODE == EP_SCALE){
    float* C = (float*)Cv + (long)z * SS * SS;
    #pragma unroll
    for (int i = 0; i < 4; i++)
      #pragma unroll
      for (int j = 0; j < 4; j++)
        #pragma unroll
        for (int r = 0; r < 4; r++)
          C[(long)(mbase + i * 16 + r) * SS + nbase + j * 16] = acc[i][j][r] * scale;
  } else if constexpr (MODE == EP_VT){
    // vT[(z*8 + b)][d = n][s]; 4 acc regs = 4 consecutive s
    u16* C = (u16*)Cv;
    #pragma unroll
    for (int i = 0; i < 4; i++){
      int mrow = mbase + i * 16;
      int b = mrow >> 9, s = mrow & (SS - 1);
      #pragma unroll
      for (int j = 0; j < 4; j++){
        int n = nbase + j * 16;
        float badd = ldf(bias, (long)z * DD + n, isbf);
        ushort4 pk;
        pk.x = f2bf(acc[i][j][0] + badd); pk.y = f2bf(acc[i][j][1] + badd);
        pk.z = f2bf(acc[i][j][2] + badd); pk.w = f2bf(acc[i][j][3] + badd);
        *(ushort4*)&C[((long)(z * 8 + b) * DD + n) * SS + s] = pk;
      }
    }
  } else if constexpr (MODE == EP_CAT){
    // cat[(b*S + s)][h*D + n]; z = h*8+b
    u16* C = (u16*)Cv;
    int h = z >> 3, b = z & 7;
    #pragma unroll
    for (int i = 0; i < 4; i++){
      int s = mbase + i * 16;
      #pragma unroll
      for (int j = 0; j < 4; j++){
        int n = nbase + j * 16;
        #pragma unroll
        for (int r = 0; r < 4; r++)
          C[((long)b * SS + s + r) * HD + (long)h * DD + n] = f2bf(acc[i][j][r]);
      }
    }
  } else if constexpr (MODE == EP_F32RES){
    float* C = (float*)Cv;
    #pragma unroll
    for (int j = 0; j < 4; j++){
      int n = nbase + j * 16;
      float badd = ldf(bias, n, isbf);
      #pragma unroll
      for (int i = 0; i < 4; i++)
        #pragma unroll
        for (int r = 0; r < 4; r++){
          long a = (long)(mbase + i * 16 + r) * ldc + n;
          C[a] = acc[i][j][r] + badd + res[a];
        }
    }
  } else if constexpr (MODE == EP_RELU){
    u16* C = (u16*)Cv;
    #pragma unroll
    for (int j = 0; j < 4; j++){
      int n = nbase + j * 16;
      float badd = ldf(bias, n, isbf);
      #pragma unroll
      for (int i = 0; i < 4; i++)
        #pragma unroll
        for (int r = 0; r < 4; r++)
          C[(long)(mbase + i * 16 + r) * ldc + n] = f2bf(fmaxf(acc[i][j][r] + badd, 0.f));
    }
  } else {
    float* O = (float*)Cv;
    #pragma unroll
    for (int j = 0; j < 4; j++){
      int n = nbase + j * 16;
      float badd = ldf(bias, n, isbf);
      #pragma unroll
      for (int i = 0; i < 4; i++)
        #pragma unroll
        for (int r = 0; r < 4; r++)
          O[(long)(mbase + i * 16 + r) * ldc + n] = acc[i][j][r] + badd;
    }
  }
}

// row softmax f32 -> bf16, 4 rows (one wave each) per block
__global__ __launch_bounds__(256) void k_softmax(const float* __restrict__ S, u16* __restrict__ P)
{
  int row = blockIdx.x * 4 + (threadIdx.x >> 6);
  int lane = threadIdx.x & 63;
  const float* p = S + (long)row * SS + lane * 8;
  float4 v0 = *(const float4*)p;
  float4 v1 = *(const float4*)(p + 4);
  float v[8] = {v0.x, v0.y, v0.z, v0.w, v1.x, v1.y, v1.z, v1.w};
  float mx = v[0];
  #pragma unroll
  for (int i = 1; i < 8; i++) mx = fmaxf(mx, v[i]);
  mx = wave_redmax(mx);
  float e[8], sum = 0.f;
  #pragma unroll
  for (int i = 0; i < 8; i++){ e[i] = expf(v[i] - mx); sum += e[i]; }
  sum = wave_redsum(sum);
  float inv = 1.f / sum;
  u16* q = P + (long)row * SS + lane * 8;
  ushort4 o0, o1;
  o0.x = f2bf(e[0] * inv); o0.y = f2bf(e[1] * inv);
  o0.z = f2bf(e[2] * inv); o0.w = f2bf(e[3] * inv);
  o1.x = f2bf(e[4] * inv); o1.y = f2bf(e[5] * inv);
  o1.z = f2bf(e[6] * inv); o1.w = f2bf(e[7] * inv);
  *(ushort4*)q = o0;
  *(ushort4*)(q + 4) = o1;
}

// LayerNorm f32 -> bf16 (+ optional f32), one wave per row of 512
template<bool WF32>
__global__ __launch_bounds__(256) void k_ln(
    const float* __restrict__ X, const void* __restrict__ g, const void* __restrict__ be,
    u16* __restrict__ Yb, float* __restrict__ Yf, const int* __restrict__ dflag)
{
  int isbf = dflag[0];
  int row = blockIdx.x * 4 + (threadIdx.x >> 6);
  int lane = threadIdx.x & 63;
  const float* p = X + (long)row * DD + lane * 8;
  float4 v0 = *(const float4*)p;
  float4 v1 = *(const float4*)(p + 4);
  float v[8] = {v0.x, v0.y, v0.z, v0.w, v1.x, v1.y, v1.z, v1.w};
  float s = 0.f;
  #pragma unroll
  for (int i = 0; i < 8; i++) s += v[i];
  s = wave_redsum(s);
  float mu = s * (1.f / DD);
  float d_[8], sq = 0.f;
  #pragma unroll
  for (int i = 0; i < 8; i++){ d_[i] = v[i] - mu; sq += d_[i] * d_[i]; }
  sq = wave_redsum(sq);
  float rs = 1.f / sqrtf(sq * (1.f / DD) + 1e-5f);
  #pragma unroll
  for (int i = 0; i < 8; i++){
    int dd = lane * 8 + i;
    float y = ldf(g, dd, isbf) * d_[i] * rs + ldf(be, dd, isbf);
    Yb[(long)row * DD + dd] = f2bf(y);
    if (WF32) Yf[(long)row * DD + dd] = y;
  }
}

extern "C" void kernel_launch(void* const* d_in, const int* in_sizes, int n_in,
                              void* d_out, int out_size, void* d_ws, size_t ws_size,
                              hipStream_t stream)
{
  const int* tokens = (const int*)d_in[0];
  const void* emb = d_in[1];
  const void* pe  = d_in[2];
  const void* Wq  = d_in[3];
  const void* bq  = d_in[4];
  const void* Wk  = d_in[5];
  const void* bk  = d_in[6];
  const void* Wv  = d_in[7];
  const void* bv  = d_in[8];
  const void* Wo  = d_in[9];
  const void* bo  = d_in[10];
  const void* g1  = d_in[11];
  const void* be1 = d_in[12];
  const void* W1  = d_in[13];
  const void* b1  = d_in[14];
  const void* W2  = d_in[15];
  const void* b2  = d_in[16];
  const void* g2  = d_in[17];
  const void* be2 = d_in[18];
  const void* Wf  = d_in[19];
  const void* bfb = d_in[20];
  float* out = (float*)d_out;   // reference output dtype = float32
  char* ws = (char*)d_ws;
  char* DO = (char*)d_out;

  const size_t MB = 1ull << 20;
  // ---- d_ws (39.3 MiB; <=69 MiB evidenced safe) ----
  int* dflag = (int*)ws;
  u16* x2b   = (u16*)(ws + 1 * MB);        // [1,5)
  u16* WfT   = (u16*)(ws + 8 * MB);        // [8,39.25)  bf16 [32000][512]

  // ---- d_out as scratch (452 of 500 MiB; all dead before logits) ----
  float* x      = (float*)(DO + 0 * MB);    // [0,8)
  u16*   xm_cat = (u16*)(DO + 8 * MB);      // [8,20)    [4096][1536] = [xh|xh|xl]
  u16*   Wq_cat = (u16*)(DO + 20 * MB);     // [20,32)   [8][512][1536] = [wh|wl|wh]
  u16*   Wk_cat = (u16*)(DO + 32 * MB);     // [32,44)
  u16*   WvT    = (u16*)(DO + 44 * MB);     // [44,48)   [8][512][512]
  u16*   WoT    = (u16*)(DO + 48 * MB);     // [48,52)   [512][4096]
  u16*   W1T    = (u16*)(DO + 52 * MB);     // [52,54)   [2048][512]
  u16*   W2T    = (u16*)(DO + 54 * MB);     // [54,56)   [512][2048]
  u16*   q_cat  = (u16*)(DO + 56 * MB);     // [56,152)  [8][4096][1536] = [qh|qh|ql]
  u16*   k_cat  = (u16*)(DO + 152 * MB);    // [152,248) [8][4096][1536] = [kh|kl|kh]
  float* sc     = (float*)(DO + 248 * MB);  // [248,312) [64][512][512]
  u16*   attn   = (u16*)(DO + 312 * MB);    // [312,344)
  u16*   vT     = (u16*)(DO + 344 * MB);    // [344,376) [64][512 d][512 s]
  u16*   cat    = (u16*)(DO + 376 * MB);    // [376,408) [4096][4096]
  float* proj   = (float*)(DO + 408 * MB);  // [408,416)
  float* x1f    = (float*)(DO + 416 * MB);  // [416,424)
  u16*   x1b    = (u16*)(DO + 424 * MB);    // [424,428)
  u16*   ff1    = (u16*)(DO + 428 * MB);    // [428,444) [4096][2048]
  float* ff2    = (float*)(DO + 444 * MB);  // [444,452)

  const float scale = 0.04419417382415922f;  // 1/sqrt(512)
  const long HSL = 262144;                   // 512*512
  const long KSL = (long)DD * KC;            // 786432 (weight-cat slice)
  const long QSL = (long)SS * KC;            // 786432 (q/k-cat per z=(h*8+b))

  k_dflag<<<1, 1, 0, stream>>>(pe, dflag);
  k_embed<<<dim3(4096), 256, 0, stream>>>(tokens, emb, pe, x, xm_cat, dflag);

  // one-time weight prep
  k_wsplitT<<<dim3(16, 16, 8), 256, 0, stream>>>(Wq, Wq_cat, dflag);
  k_wsplitT<<<dim3(16, 16, 8), 256, 0, stream>>>(Wk, Wk_cat, dflag);
  k_transT<<<dim3(16, 16, 8), 256, 0, stream>>>(Wv, WvT, 512, 512, dflag);
  k_transT<<<dim3(16, 128, 1), 256, 0, stream>>>(Wo, WoT, 4096, 512, dflag);
  k_transT<<<dim3(64, 16, 1), 256, 0, stream>>>(W1, W1T, 512, 2048, dflag);
  k_transT<<<dim3(16, 64, 1), 256, 0, stream>>>(W2, W2T, 2048, 512, dflag);
  k_transT<<<dim3(1000, 16, 1), 256, 0, stream>>>(Wf, WfT, 512, 32000, dflag);

  // q/k projections, exact via split-concat K=1536 (writes activation splits)
  k_mfma<EP_QCAT, false><<<dim3(4, 32, 8), 256, 0, stream>>>(
      xm_cat, 0, KC, Wq_cat, KSL, q_cat, bq, nullptr, KC, 0, 0.f, dflag);
  k_mfma<EP_KCAT, false><<<dim3(4, 32, 8), 256, 0, stream>>>(
      xm_cat, 0, KC, Wk_cat, KSL, k_cat, bk, nullptr, KC, 0, 0.f, dflag);
  // v projection (bf16-hi input is band0 of xm_cat, lda=1536)
  k_mfma<EP_VT, false><<<dim3(4, 32, 8), 256, 0, stream>>>(
      xm_cat, 0, KC, WvT, HSL, vT, bv, nullptr, DD, 0, 0.f, dflag);

  // scores = q_cat . k_cat^T * scale (exact to ~2^-16), z = h*8+b
  k_mfma<EP_SCALE, false><<<dim3(4, 4, 64), 256, 0, stream>>>(
      q_cat, QSL, KC, k_cat, QSL, sc, nullptr, nullptr, KC, 0, scale, dflag);
  k_softmax<<<dim3(8192), 256, 0, stream>>>(sc, attn);

  // o = attn @ v -> cat (torch.cat head order)
  k_mfma<EP_CAT, false><<<dim3(4, 4, 64), 256, 0, stream>>>(
      attn, HSL, SS, vT, HSL, cat, nullptr, nullptr, SS, 0, 0.f, dflag);

  // proj = cat @ Wo + bo + x
  k_mfma<EP_F32RES, false><<<dim3(4, 32, 1), 256, 0, stream>>>(
      cat, 0, HD, WoT, 0, proj, bo, x, HD, DD, 0.f, dflag);
  k_ln<true><<<dim3(1024), 256, 0, stream>>>(proj, g1, be1, x1b, x1f, dflag);

  // ff = relu(x1 @ W1 + b1) @ W2 + b2 + x1
  k_mfma<EP_RELU, false><<<dim3(16, 32, 1), 256, 0, stream>>>(
      x1b, 0, DD, W1T, 0, ff1, b1, nullptr, DD, NFF, 0.f, dflag);
  k_mfma<EP_F32RES, false><<<dim3(4, 32, 1), 256, 0, stream>>>(
      ff1, 0, NFF, W2T, 0, ff2, b2, x1f, NFF, DD, 0.f, dflag);
  k_ln<false><<<dim3(1024), 256, 0, stream>>>(ff2, g2, be2, x2b, nullptr, dflag);

  // logits = x2 @ Wf + bf -> f32 out (reads only ws + raw inputs)
  k_mfma<EP_OUT, true><<<dim3(32, 250, 1), 256, 0, stream>>>(
      x2b, 0, DD, WfT, 0, out, bfb, nullptr, DD, VV, 0.f, dflag);
}

// Round 8
// 1279.568 us; speedup vs baseline: 2.7632x; 1.0540x over previous
//
#include <hip/hip_runtime.h>

typedef unsigned short u16;
typedef unsigned int u32;
typedef short s16x8 __attribute__((ext_vector_type(8)));
typedef __bf16 bf16x8 __attribute__((ext_vector_type(8)));
typedef float f32x4 __attribute__((ext_vector_type(4)));

#define DEVI static __device__ __forceinline__

#define SS 512
#define DD 512
#define NFF 2048
#define VV 32000
#define MTOT 4096
#define HD 4096
#define KC 1536   // split-concat K

DEVI float bf2f(u16 h){ return __uint_as_float(((u32)h) << 16); }
DEVI u16 f2bf(float f){
  u32 u = __float_as_uint(f);
  return (u16)((u + 0x7FFFu + ((u >> 16) & 1u)) >> 16);
}
DEVI float ldf(const void* p, long i, int isbf){
  return isbf ? bf2f(((const u16*)p)[i]) : ((const float*)p)[i];
}

DEVI f32x4 mfma16(s16x8 a, s16x8 b, f32x4 c){
  return __builtin_amdgcn_mfma_f32_16x16x32_bf16(
      __builtin_bit_cast(bf16x8, a), __builtin_bit_cast(bf16x8, b), c, 0, 0, 0);
}

// direct global->LDS 16B copy; dst is wave-uniform base + lane*16, src per-lane
typedef const __attribute__((address_space(1))) unsigned int* gup;
typedef __attribute__((address_space(3))) unsigned int* lup;
DEVI void gload16(const void* g, void* l){
  __builtin_amdgcn_global_load_lds((gup)g, (lup)l, 16, 0, 0);
}

DEVI float wave_redmax(float v){
  #pragma unroll
  for (int off = 32; off > 0; off >>= 1) v = fmaxf(v, __shfl_xor(v, off, 64));
  return v;
}
DEVI float wave_redsum(float v){
  #pragma unroll
  for (int off = 32; off > 0; off >>= 1) v += __shfl_xor(v, off, 64);
  return v;
}

// pe row0 = [sin0=0, cos0=1, ...]: first u32 word = 0x3F800000 if bf16, 0x00000000 if f32
__global__ void k_dflag(const void* pe, int* flag){
  flag[0] = (*(const u32*)pe == 0x3F800000u) ? 1 : 0;
}

// embed + residual + masked split-concat: xm_cat[m][0:512]=hi, [512:1024]=hi, [1024:1536]=lo
__global__ __launch_bounds__(256) void k_embed(
    const int* __restrict__ tok, const void* __restrict__ emb, const void* __restrict__ pe,
    float* __restrict__ x, u16* __restrict__ xm_cat, const int* __restrict__ dflag)
{
  int isbf = dflag[0];
  int blk = blockIdx.x;
  int s = blk & (SS - 1);
  int t = tok[blk];
  long rb = (long)blk * KC;
  for (int d = threadIdx.x; d < DD; d += 256){
    float e = ldf(emb, (long)t * DD + d, isbf) + ldf(pe, (long)s * DD + d, isbf);
    x[(long)blk * DD + d] = e;
    float m = (d <= s) ? e : 0.f;           // triu(ones(S,D),k=1) zeroes d > s
    u16 hi = f2bf(m);
    u16 lo = f2bf(m - bf2f(hi));
    xm_cat[rb + d] = hi;
    xm_cat[rb + 512 + d] = hi;
    xm_cat[rb + 1024 + d] = lo;
  }
}

// split-transpose for Wq/Wk: in W[z][512 d][512 e] -> out[z][512 e][1536]:
// band0[e][d]=hi, band1[e][d]=lo, band2[e][d]=hi   (matches A=[xh|xh|xl])
__global__ __launch_bounds__(256) void k_wsplitT(
    const void* __restrict__ in, u16* __restrict__ out, const int* __restrict__ dflag)
{
  int isbf = dflag[0];
  long zin = (long)blockIdx.z * DD * DD;
  long zout = (long)blockIdx.z * DD * KC;
  __shared__ float t[32][33];
  int e0 = blockIdx.x * 32, d0 = blockIdx.y * 32;
  int tx = threadIdx.x & 31, ty = threadIdx.x >> 5;
  #pragma unroll
  for (int i = 0; i < 4; i++){
    int d = ty + i * 8;
    t[d][tx] = ldf(in, zin + (long)(d0 + d) * DD + e0 + tx, isbf);
  }
  __syncthreads();
  #pragma unroll
  for (int i = 0; i < 4; i++){
    int e = ty + i * 8;
    float v = t[tx][e];
    u16 hi = f2bf(v);
    u16 lo = f2bf(v - bf2f(hi));
    long ob = zout + (long)(e0 + e) * KC + d0 + tx;
    out[ob] = hi;
    out[ob + 512] = lo;
    out[ob + 1024] = hi;
  }
}

// plain transpose f32/bf16 -> bf16: in [R][C] (+z*R*C) -> out [C][R] (+z*R*C)
__global__ __launch_bounds__(256) void k_transT(
    const void* __restrict__ in, u16* __restrict__ out, int R, int C,
    const int* __restrict__ dflag)
{
  int isbf = dflag[0];
  long zo = (long)blockIdx.z * R * C;
  __shared__ float t[32][33];
  int c0 = blockIdx.x * 32, r0 = blockIdx.y * 32;
  int tx = threadIdx.x & 31, ty = threadIdx.x >> 5;
  #pragma unroll
  for (int i = 0; i < 4; i++){
    int r = ty + i * 8;
    t[r][tx] = ldf(in, zo + (long)(r0 + r) * C + c0 + tx, isbf);
  }
  __syncthreads();
  #pragma unroll
  for (int i = 0; i < 4; i++){
    int c = ty + i * 8;
    out[zo + (long)(c0 + c) * R + r0 + tx] = f2bf(t[tx][c]);
  }
}

enum { EP_QCAT = 0, EP_KCAT = 1, EP_SCALE = 2, EP_VT = 3, EP_CAT = 4,
       EP_F32RES = 5, EP_RELU = 6, EP_OUT = 7 };

// bf16 MFMA GEMM: C = A[.][K](lda) @ Bt[N][K]^T. 128x128 tile, BK=32, 4 waves,
// 16x16x32 MFMA, global_load_lds staging, double-buffered LDS (2-phase T3):
// next tile's loads issued BEFORE current tile's ds_read+MFMA; ONE barrier/step.
template<int MODE, bool GSWAP>
__global__ __launch_bounds__(256) void k_mfma(
    const u16* __restrict__ A, long sA, int lda,
    const u16* __restrict__ Bt, long sB,
    void* __restrict__ Cv,
    const void* __restrict__ bias,
    const float* __restrict__ res,
    int K, int ldc, float scale,
    const int* __restrict__ dflag)
{
  int isbf = dflag[0];
  int z = blockIdx.z;
  const u16* Ab = A + (long)z * sA;
  const u16* Bb = Bt + (long)z * sB;
  __shared__ __align__(16) u16 As[2][4][128][8];   // 2 buffers x 8 KB
  __shared__ __align__(16) u16 Bs[2][4][128][8];
  int m0 = (GSWAP ? blockIdx.x : blockIdx.y) * 128;
  int n0 = (GSWAP ? blockIdx.y : blockIdx.x) * 128;
  int tid = threadIdx.x;
  int lane = tid & 63, w = tid >> 6;
  int wr = (w >> 1) * 64, wc = (w & 1) * 64;
  int l15 = lane & 15, l4 = lane >> 4;
  int s0 = w * 64 + lane;                 // slots 0..255
  int ar0 = s0 & 127, ak0 = s0 >> 7;      // skc 0..1
  int ak1 = ak0 + 2;                      // slots 256..511: same row, skc 2..3
  f32x4 zero = {0.f, 0.f, 0.f, 0.f};
  f32x4 acc[4][4];
  #pragma unroll
  for (int i = 0; i < 4; i++)
    #pragma unroll
    for (int j = 0; j < 4; j++) acc[i][j] = zero;

  const long arow0 = (long)(m0 + ar0) * lda;
  const long brow0 = (long)(n0 + ar0) * K;

  #define STAGE(buf, k0) do{ \
    u16* AsF = &As[buf][0][0][0]; \
    u16* BsF = &Bs[buf][0][0][0]; \
    gload16(Ab + arow0 + (k0) + ak0 * 8, AsF + (long)(w * 64) * 8); \
    gload16(Ab + arow0 + (k0) + ak1 * 8, AsF + (long)(256 + w * 64) * 8); \
    gload16(Bb + brow0 + (k0) + ak0 * 8, BsF + (long)(w * 64) * 8); \
    gload16(Bb + brow0 + (k0) + ak1 * 8, BsF + (long)(256 + w * 64) * 8); \
  }while(0)

  #define COMPUTE(buf) do{ \
    s16x8 af[4], bfr[4]; \
    _Pragma("unroll") \
    for (int i = 0; i < 4; i++) af[i] = *(const s16x8*)&As[buf][l4][wr + i * 16 + l15][0]; \
    _Pragma("unroll") \
    for (int j = 0; j < 4; j++) bfr[j] = *(const s16x8*)&Bs[buf][l4][wc + j * 16 + l15][0]; \
    _Pragma("unroll") \
    for (int i = 0; i < 4; i++) \
      _Pragma("unroll") \
      for (int j = 0; j < 4; j++) \
        acc[i][j] = mfma16(af[i], bfr[j], acc[i][j]); \
  }while(0)

  // K is a multiple of 64 in every use -> even number of BK=32 steps
  STAGE(0, 0);
  __syncthreads();                 // buf0 ready (vmcnt drained by barrier)
  for (int k0 = 0; k0 < K; k0 += 64){
    STAGE(1, k0 + 32);             // issue next tile's loads first
    COMPUTE(0);                    // overlap: MFMA on buf0 while buf1 loads fly
    __syncthreads();               // buf1 ready; all reads of buf0 done
    if (k0 + 64 < K) STAGE(0, k0 + 64);
    COMPUTE(1);
    __syncthreads();
  }
  #undef STAGE
  #undef COMPUTE

  int mbase = m0 + wr + l4 * 4;   // C row = mbase + i*16 + r
  int nbase = n0 + wc + l15;      // C col = nbase + j*16
  if constexpr (MODE == EP_QCAT || MODE == EP_KCAT){
    u16* C = (u16*)Cv + (long)z * ((long)MTOT * KC);
    #pragma unroll
    for (int j = 0; j < 4; j++){
      int n = nbase + j * 16;
      float badd = ldf(bias, (long)z * DD + n, isbf);
      #pragma unroll
      for (int i = 0; i < 4; i++)
        #pragma unroll
        for (int r = 0; r < 4; r++){
          float qv = acc[i][j][r] + badd;
          u16 hi = f2bf(qv);
          u16 lo = f2bf(qv - bf2f(hi));
          long rb = (long)(mbase + i * 16 + r) * KC;
          C[rb + n] = hi;
          if constexpr (MODE == EP_QCAT){ C[rb + 512 + n] = hi; C[rb + 1024 + n] = lo; }
          else                          { C[rb + 512 + n] = lo; C[rb + 1024 + n] = hi; }
        }
    }
  } else if constexpr (MODE == EP_SCALE){
    float* C = (float*)Cv + (long)z * SS * SS;
    #pragma unroll
    for (int i = 0; i < 4; i++)
      #pragma unroll
      for (int j = 0; j < 4; j++)
        #pragma unroll
        for (int r = 0; r < 4; r++)
          C[(long)(mbase + i * 16 + r) * SS + nbase + j * 16] = acc[i][j][r] * scale;
  } else if constexpr (MODE == EP_VT){
    // vT[(z*8 + b)][d = n][s]; 4 acc regs = 4 consecutive s
    u16* C = (u16*)Cv;
    #pragma unroll
    for (int i = 0; i < 4; i++){
      int mrow = mbase + i * 16;
      int b = mrow >> 9, s = mrow & (SS - 1);
      #pragma unroll
      for (int j = 0; j < 4; j++){
        int n = nbase + j * 16;
        float badd = ldf(bias, (long)z * DD + n, isbf);
        ushort4 pk;
        pk.x = f2bf(acc[i][j][0] + badd); pk.y = f2bf(acc[i][j][1] + badd);
        pk.z = f2bf(acc[i][j][2] + badd); pk.w = f2bf(acc[i][j][3] + badd);
        *(ushort4*)&C[((long)(z * 8 + b) * DD + n) * SS + s] = pk;
      }
    }
  } else if constexpr (MODE == EP_CAT){
    // cat[(b*S + s)][h*D + n]; z = h*8+b
    u16* C = (u16*)Cv;
    int h = z >> 3, b = z & 7;
    #pragma unroll
    for (int i = 0; i < 4; i++){
      int s = mbase + i * 16;
      #pragma unroll
      for (int j = 0; j < 4; j++){
        int n = nbase + j * 16;
        #pragma unroll
        for (int r = 0; r < 4; r++)
          C[((long)b * SS + s + r) * HD + (long)h * DD + n] = f2bf(acc[i][j][r]);
      }
    }
  } else if constexpr (MODE == EP_F32RES){
    float* C = (float*)Cv;
    #pragma unroll
    for (int j = 0; j < 4; j++){
      int n = nbase + j * 16;
      float badd = ldf(bias, n, isbf);
      #pragma unroll
      for (int i = 0; i < 4; i++)
        #pragma unroll
        for (int r = 0; r < 4; r++){
          long a = (long)(mbase + i * 16 + r) * ldc + n;
          C[a] = acc[i][j][r] + badd + res[a];
        }
    }
  } else if constexpr (MODE == EP_RELU){
    u16* C = (u16*)Cv;
    #pragma unroll
    for (int j = 0; j < 4; j++){
      int n = nbase + j * 16;
      float badd = ldf(bias, n, isbf);
      #pragma unroll
      for (int i = 0; i < 4; i++)
        #pragma unroll
        for (int r = 0; r < 4; r++)
          C[(long)(mbase + i * 16 + r) * ldc + n] = f2bf(fmaxf(acc[i][j][r] + badd, 0.f));
    }
  } else {
    float* O = (float*)Cv;
    #pragma unroll
    for (int j = 0; j < 4; j++){
      int n = nbase + j * 16;
      float badd = ldf(bias, n, isbf);
      #pragma unroll
      for (int i = 0; i < 4; i++)
        #pragma unroll
        for (int r = 0; r < 4; r++)
          O[(long)(mbase + i * 16 + r) * ldc + n] = acc[i][j][r] + badd;
    }
  }
}

// row softmax f32 -> bf16, 4 rows (one wave each) per block
__global__ __launch_bounds__(256) void k_softmax(const float* __restrict__ S, u16* __restrict__ P)
{
  int row = blockIdx.x * 4 + (threadIdx.x >> 6);
  int lane = threadIdx.x & 63;
  const float* p = S + (long)row * SS + lane * 8;
  float4 v0 = *(const float4*)p;
  float4 v1 = *(const float4*)(p + 4);
  float v[8] = {v0.x, v0.y, v0.z, v0.w, v1.x, v1.y, v1.z, v1.w};
  float mx = v[0];
  #pragma unroll
  for (int i = 1; i < 8; i++) mx = fmaxf(mx, v[i]);
  mx = wave_redmax(mx);
  float e[8], sum = 0.f;
  #pragma unroll
  for (int i = 0; i < 8; i++){ e[i] = expf(v[i] - mx); sum += e[i]; }
  sum = wave_redsum(sum);
  float inv = 1.f / sum;
  u16* q = P + (long)row * SS + lane * 8;
  ushort4 o0, o1;
  o0.x = f2bf(e[0] * inv); o0.y = f2bf(e[1] * inv);
  o0.z = f2bf(e[2] * inv); o0.w = f2bf(e[3] * inv);
  o1.x = f2bf(e[4] * inv); o1.y = f2bf(e[5] * inv);
  o1.z = f2bf(e[6] * inv); o1.w = f2bf(e[7] * inv);
  *(ushort4*)q = o0;
  *(ushort4*)(q + 4) = o1;
}

// LayerNorm f32 -> bf16 (+ optional f32), one wave per row of 512
template<bool WF32>
__global__ __launch_bounds__(256) void k_ln(
    const float* __restrict__ X, const void* __restrict__ g, const void* __restrict__ be,
    u16* __restrict__ Yb, float* __restrict__ Yf, const int* __restrict__ dflag)
{
  int isbf = dflag[0];
  int row = blockIdx.x * 4 + (threadIdx.x >> 6);
  int lane = threadIdx.x & 63;
  const float* p = X + (long)row * DD + lane * 8;
  float4 v0 = *(const float4*)p;
  float4 v1 = *(const float4*)(p + 4);
  float v[8] = {v0.x, v0.y, v0.z, v0.w, v1.x, v1.y, v1.z, v1.w};
  float s = 0.f;
  #pragma unroll
  for (int i = 0; i < 8; i++) s += v[i];
  s = wave_redsum(s);
  float mu = s * (1.f / DD);
  float d_[8], sq = 0.f;
  #pragma unroll
  for (int i = 0; i < 8; i++){ d_[i] = v[i] - mu; sq += d_[i] * d_[i]; }
  sq = wave_redsum(sq);
  float rs = 1.f / sqrtf(sq * (1.f / DD) + 1e-5f);
  #pragma unroll
  for (int i = 0; i < 8; i++){
    int dd = lane * 8 + i;
    float y = ldf(g, dd, isbf) * d_[i] * rs + ldf(be, dd, isbf);
    Yb[(long)row * DD + dd] = f2bf(y);
    if (WF32) Yf[(long)row * DD + dd] = y;
  }
}

extern "C" void kernel_launch(void* const* d_in, const int* in_sizes, int n_in,
                              void* d_out, int out_size, void* d_ws, size_t ws_size,
                              hipStream_t stream)
{
  const int* tokens = (const int*)d_in[0];
  const void* emb = d_in[1];
  const void* pe  = d_in[2];
  const void* Wq  = d_in[3];
  const void* bq  = d_in[4];
  const void* Wk  = d_in[5];
  const void* bk  = d_in[6];
  const void* Wv  = d_in[7];
  const void* bv  = d_in[8];
  const void* Wo  = d_in[9];
  const void* bo  = d_in[10];
  const void* g1  = d_in[11];
  const void* be1 = d_in[12];
  const void* W1  = d_in[13];
  const void* b1  = d_in[14];
  const void* W2  = d_in[15];
  const void* b2  = d_in[16];
  const void* g2  = d_in[17];
  const void* be2 = d_in[18];
  const void* Wf  = d_in[19];
  const void* bfb = d_in[20];
  float* out = (float*)d_out;   // reference output dtype = float32
  char* ws = (char*)d_ws;
  char* DO = (char*)d_out;

  const size_t MB = 1ull << 20;
  // ---- d_ws (39.3 MiB; <=69 MiB evidenced safe) ----
  int* dflag = (int*)ws;
  u16* x2b   = (u16*)(ws + 1 * MB);        // [1,5)
  u16* WfT   = (u16*)(ws + 8 * MB);        // [8,39.25)  bf16 [32000][512]

  // ---- d_out as scratch (452 of 500 MiB; all dead before logits) ----
  float* x      = (float*)(DO + 0 * MB);    // [0,8)
  u16*   xm_cat = (u16*)(DO + 8 * MB);      // [8,20)    [4096][1536] = [xh|xh|xl]
  u16*   Wq_cat = (u16*)(DO + 20 * MB);     // [20,32)   [8][512][1536] = [wh|wl|wh]
  u16*   Wk_cat = (u16*)(DO + 32 * MB);     // [32,44)
  u16*   WvT    = (u16*)(DO + 44 * MB);     // [44,48)   [8][512][512]
  u16*   WoT    = (u16*)(DO + 48 * MB);     // [48,52)   [512][4096]
  u16*   W1T    = (u16*)(DO + 52 * MB);     // [52,54)   [2048][512]
  u16*   W2T    = (u16*)(DO + 54 * MB);     // [54,56)   [512][2048]
  u16*   q_cat  = (u16*)(DO + 56 * MB);     // [56,152)  [8][4096][1536] = [qh|qh|ql]
  u16*   k_cat  = (u16*)(DO + 152 * MB);    // [152,248) [8][4096][1536] = [kh|kl|kh]
  float* sc     = (float*)(DO + 248 * MB);  // [248,312) [64][512][512]
  u16*   attn   = (u16*)(DO + 312 * MB);    // [312,344)
  u16*   vT     = (u16*)(DO + 344 * MB);    // [344,376) [64][512 d][512 s]
  u16*   cat    = (u16*)(DO + 376 * MB);    // [376,408) [4096][4096]
  float* proj   = (float*)(DO + 408 * MB);  // [408,416)
  float* x1f    = (float*)(DO + 416 * MB);  // [416,424)
  u16*   x1b    = (u16*)(DO + 424 * MB);    // [424,428)
  u16*   ff1    = (u16*)(DO + 428 * MB);    // [428,444) [4096][2048]
  float* ff2    = (float*)(DO + 444 * MB);  // [444,452)

  const float scale = 0.04419417382415922f;  // 1/sqrt(512)
  const long HSL = 262144;                   // 512*512
  const long KSL = (long)DD * KC;            // weight-cat slice
  const long QSL = (long)SS * KC;            // q/k-cat per z=(h*8+b)

  k_dflag<<<1, 1, 0, stream>>>(pe, dflag);
  k_embed<<<dim3(4096), 256, 0, stream>>>(tokens, emb, pe, x, xm_cat, dflag);

  // one-time weight prep
  k_wsplitT<<<dim3(16, 16, 8), 256, 0, stream>>>(Wq, Wq_cat, dflag);
  k_wsplitT<<<dim3(16, 16, 8), 256, 0, stream>>>(Wk, Wk_cat, dflag);
  k_transT<<<dim3(16, 16, 8), 256, 0, stream>>>(Wv, WvT, 512, 512, dflag);
  k_transT<<<dim3(16, 128, 1), 256, 0, stream>>>(Wo, WoT, 4096, 512, dflag);
  k_transT<<<dim3(64, 16, 1), 256, 0, stream>>>(W1, W1T, 512, 2048, dflag);
  k_transT<<<dim3(16, 64, 1), 256, 0, stream>>>(W2, W2T, 2048, 512, dflag);
  k_transT<<<dim3(1000, 16, 1), 256, 0, stream>>>(Wf, WfT, 512, 32000, dflag);

  // q/k projections, exact via split-concat K=1536 (writes activation splits)
  k_mfma<EP_QCAT, false><<<dim3(4, 32, 8), 256, 0, stream>>>(
      xm_cat, 0, KC, Wq_cat, KSL, q_cat, bq, nullptr, KC, 0, 0.f, dflag);
  k_mfma<EP_KCAT, false><<<dim3(4, 32, 8), 256, 0, stream>>>(
      xm_cat, 0, KC, Wk_cat, KSL, k_cat, bk, nullptr, KC, 0, 0.f, dflag);
  // v projection (bf16-hi input is band0 of xm_cat, lda=1536)
  k_mfma<EP_VT, false><<<dim3(4, 32, 8), 256, 0, stream>>>(
      xm_cat, 0, KC, WvT, HSL, vT, bv, nullptr, DD, 0, 0.f, dflag);

  // scores = q_cat . k_cat^T * scale (exact to ~2^-16), z = h*8+b
  k_mfma<EP_SCALE, false><<<dim3(4, 4, 64), 256, 0, stream>>>(
      q_cat, QSL, KC, k_cat, QSL, sc, nullptr, nullptr, KC, 0, scale, dflag);
  k_softmax<<<dim3(8192), 256, 0, stream>>>(sc, attn);

  // o = attn @ v -> cat (torch.cat head order)
  k_mfma<EP_CAT, false><<<dim3(4, 4, 64), 256, 0, stream>>>(
      attn, HSL, SS, vT, HSL, cat, nullptr, nullptr, SS, 0, 0.f, dflag);

  // proj = cat @ Wo + bo + x
  k_mfma<EP_F32RES, false><<<dim3(4, 32, 1), 256, 0, stream>>>(
      cat, 0, HD, WoT, 0, proj, bo, x, HD, DD, 0.f, dflag);
  k_ln<true><<<dim3(1024), 256, 0, stream>>>(proj, g1, be1, x1b, x1f, dflag);

  // ff = relu(x1 @ W1 + b1) @ W2 + b2 + x1
  k_mfma<EP_RELU, false><<<dim3(16, 32, 1), 256, 0, stream>>>(
      x1b, 0, DD, W1T, 0, ff1, b1, nullptr, DD, NFF, 0.f, dflag);
  k_mfma<EP_F32RES, false><<<dim3(4, 32, 1), 256, 0, stream>>>(
      ff1, 0, NFF, W2T, 0, ff2, b2, x1f, NFF, DD, 0.f, dflag);
  k_ln<false><<<dim3(1024), 256, 0, stream>>>(ff2, g2, be2, x2b, nullptr, dflag);

  // logits = x2 @ Wf + bf -> f32 out (reads only ws + raw inputs)
  k_mfma<EP_OUT, true><<<dim3(32, 250, 1), 256, 0, stream>>>(
      x2b, 0, DD, WfT, 0, out, bfb, nullptr, DD, VV, 0.f, dflag);
}

// Round 9
// 1170.710 us; speedup vs baseline: 3.0202x; 1.0930x over previous
//
#include <hip/hip_runtime.h>

typedef unsigned short u16;
typedef unsigned int u32;
typedef short s16x8 __attribute__((ext_vector_type(8)));
typedef __bf16 bf16x8 __attribute__((ext_vector_type(8)));
typedef float f32x4 __attribute__((ext_vector_type(4)));

#define DEVI static __device__ __forceinline__

#define SS 512
#define DD 512
#define NFF 2048
#define VV 32000
#define MTOT 4096
#define HD 4096
#define KC 1536   // split-concat K

DEVI float bf2f(u16 h){ return __uint_as_float(((u32)h) << 16); }
DEVI u16 f2bf(float f){
  u32 u = __float_as_uint(f);
  return (u16)((u + 0x7FFFu + ((u >> 16) & 1u)) >> 16);
}
DEVI float ldf(const void* p, long i, int isbf){
  return isbf ? bf2f(((const u16*)p)[i]) : ((const float*)p)[i];
}

DEVI f32x4 mfma16(s16x8 a, s16x8 b, f32x4 c){
  return __builtin_amdgcn_mfma_f32_16x16x32_bf16(
      __builtin_bit_cast(bf16x8, a), __builtin_bit_cast(bf16x8, b), c, 0, 0, 0);
}

// direct global->LDS 16B copy; dst is wave-uniform base + lane*16, src per-lane
typedef const __attribute__((address_space(1))) unsigned int* gup;
typedef __attribute__((address_space(3))) unsigned int* lup;
DEVI void gload16(const void* g, void* l){
  __builtin_amdgcn_global_load_lds((gup)g, (lup)l, 16, 0, 0);
}

DEVI float wave_redmax(float v){
  #pragma unroll
  for (int off = 32; off > 0; off >>= 1) v = fmaxf(v, __shfl_xor(v, off, 64));
  return v;
}
DEVI float wave_redsum(float v){
  #pragma unroll
  for (int off = 32; off > 0; off >>= 1) v += __shfl_xor(v, off, 64);
  return v;
}

// pe row0 = [sin0=0, cos0=1, ...]: first u32 word = 0x3F800000 if bf16, 0x00000000 if f32
__global__ void k_dflag(const void* pe, int* flag){
  flag[0] = (*(const u32*)pe == 0x3F800000u) ? 1 : 0;
}

// embed + residual + masked split-concat: xm_cat[m][0:512]=hi, [512:1024]=hi, [1024:1536]=lo
__global__ __launch_bounds__(256) void k_embed(
    const int* __restrict__ tok, const void* __restrict__ emb, const void* __restrict__ pe,
    float* __restrict__ x, u16* __restrict__ xm_cat, const int* __restrict__ dflag)
{
  int isbf = dflag[0];
  int blk = blockIdx.x;
  int s = blk & (SS - 1);
  int t = tok[blk];
  long rb = (long)blk * KC;
  for (int d = threadIdx.x; d < DD; d += 256){
    float e = ldf(emb, (long)t * DD + d, isbf) + ldf(pe, (long)s * DD + d, isbf);
    x[(long)blk * DD + d] = e;
    float m = (d <= s) ? e : 0.f;           // triu(ones(S,D),k=1) zeroes d > s
    u16 hi = f2bf(m);
    u16 lo = f2bf(m - bf2f(hi));
    xm_cat[rb + d] = hi;
    xm_cat[rb + 512 + d] = hi;
    xm_cat[rb + 1024 + d] = lo;
  }
}

// split-transpose for Wq/Wk: in W[z][512 d][512 e] -> out[z][512 e][1536]:
// band0[e][d]=hi, band1[e][d]=lo, band2[e][d]=hi   (matches A=[xh|xh|xl])
__global__ __launch_bounds__(256) void k_wsplitT(
    const void* __restrict__ in, u16* __restrict__ out, const int* __restrict__ dflag)
{
  int isbf = dflag[0];
  long zin = (long)blockIdx.z * DD * DD;
  long zout = (long)blockIdx.z * DD * KC;
  __shared__ float t[32][33];
  int e0 = blockIdx.x * 32, d0 = blockIdx.y * 32;
  int tx = threadIdx.x & 31, ty = threadIdx.x >> 5;
  #pragma unroll
  for (int i = 0; i < 4; i++){
    int d = ty + i * 8;
    t[d][tx] = ldf(in, zin + (long)(d0 + d) * DD + e0 + tx, isbf);
  }
  __syncthreads();
  #pragma unroll
  for (int i = 0; i < 4; i++){
    int e = ty + i * 8;
    float v = t[tx][e];
    u16 hi = f2bf(v);
    u16 lo = f2bf(v - bf2f(hi));
    long ob = zout + (long)(e0 + e) * KC + d0 + tx;
    out[ob] = hi;
    out[ob + 512] = lo;
    out[ob + 1024] = hi;
  }
}

// plain transpose f32/bf16 -> bf16: in [R][C] (+z*R*C) -> out [C][R] (+z*R*C)
__global__ __launch_bounds__(256) void k_transT(
    const void* __restrict__ in, u16* __restrict__ out, int R, int C,
    const int* __restrict__ dflag)
{
  int isbf = dflag[0];
  long zo = (long)blockIdx.z * R * C;
  __shared__ float t[32][33];
  int c0 = blockIdx.x * 32, r0 = blockIdx.y * 32;
  int tx = threadIdx.x & 31, ty = threadIdx.x >> 5;
  #pragma unroll
  for (int i = 0; i < 4; i++){
    int r = ty + i * 8;
    t[r][tx] = ldf(in, zo + (long)(r0 + r) * C + c0 + tx, isbf);
  }
  __syncthreads();
  #pragma unroll
  for (int i = 0; i < 4; i++){
    int c = ty + i * 8;
    out[zo + (long)(c0 + c) * R + r0 + tx] = f2bf(t[tx][c]);
  }
}

enum { EP_QCAT = 0, EP_KCAT = 1, EP_SCALE = 2, EP_VT = 3, EP_CAT = 4,
       EP_F32RES = 5, EP_RELU = 6, EP_OUT = 7 };

// ---------- 128x128 tile, 4 waves (kept for small-N GEMMs: Wo, FF1, FF2) ----------
template<int MODE, bool GSWAP>
__global__ __launch_bounds__(256) void k_mfma(
    const u16* __restrict__ A, long sA, int lda,
    const u16* __restrict__ Bt, long sB,
    void* __restrict__ Cv,
    const void* __restrict__ bias,
    const float* __restrict__ res,
    int K, int ldc, float scale,
    const int* __restrict__ dflag)
{
  int isbf = dflag[0];
  int z = blockIdx.z;
  const u16* Ab = A + (long)z * sA;
  const u16* Bb = Bt + (long)z * sB;
  __shared__ __align__(16) u16 As[2][4][128][8];
  __shared__ __align__(16) u16 Bs[2][4][128][8];
  int m0 = (GSWAP ? blockIdx.x : blockIdx.y) * 128;
  int n0 = (GSWAP ? blockIdx.y : blockIdx.x) * 128;
  int tid = threadIdx.x;
  int lane = tid & 63, w = tid >> 6;
  int wr = (w >> 1) * 64, wc = (w & 1) * 64;
  int l15 = lane & 15, l4 = lane >> 4;
  int s0 = w * 64 + lane;
  int ar0 = s0 & 127, ak0 = s0 >> 7;
  int ak1 = ak0 + 2;
  f32x4 zero = {0.f, 0.f, 0.f, 0.f};
  f32x4 acc[4][4];
  #pragma unroll
  for (int i = 0; i < 4; i++)
    #pragma unroll
    for (int j = 0; j < 4; j++) acc[i][j] = zero;

  const long arow0 = (long)(m0 + ar0) * lda;
  const long brow0 = (long)(n0 + ar0) * K;

  #define STAGE(buf, k0) do{ \
    u16* AsF = &As[buf][0][0][0]; \
    u16* BsF = &Bs[buf][0][0][0]; \
    gload16(Ab + arow0 + (k0) + ak0 * 8, AsF + (long)(w * 64) * 8); \
    gload16(Ab + arow0 + (k0) + ak1 * 8, AsF + (long)(256 + w * 64) * 8); \
    gload16(Bb + brow0 + (k0) + ak0 * 8, BsF + (long)(w * 64) * 8); \
    gload16(Bb + brow0 + (k0) + ak1 * 8, BsF + (long)(256 + w * 64) * 8); \
  }while(0)

  #define COMPUTE(buf) do{ \
    s16x8 af[4], bfr[4]; \
    _Pragma("unroll") \
    for (int i = 0; i < 4; i++) af[i] = *(const s16x8*)&As[buf][l4][wr + i * 16 + l15][0]; \
    _Pragma("unroll") \
    for (int j = 0; j < 4; j++) bfr[j] = *(const s16x8*)&Bs[buf][l4][wc + j * 16 + l15][0]; \
    _Pragma("unroll") \
    for (int i = 0; i < 4; i++) \
      _Pragma("unroll") \
      for (int j = 0; j < 4; j++) \
        acc[i][j] = mfma16(af[i], bfr[j], acc[i][j]); \
  }while(0)

  STAGE(0, 0);
  __syncthreads();
  for (int k0 = 0; k0 < K; k0 += 64){
    STAGE(1, k0 + 32);
    COMPUTE(0);
    __syncthreads();
    if (k0 + 64 < K) STAGE(0, k0 + 64);
    COMPUTE(1);
    __syncthreads();
  }
  #undef STAGE
  #undef COMPUTE

  int mbase = m0 + wr + l4 * 4;
  int nbase = n0 + wc + l15;
  if constexpr (MODE == EP_F32RES){
    float* C = (float*)Cv;
    #pragma unroll
    for (int j = 0; j < 4; j++){
      int n = nbase + j * 16;
      float badd = ldf(bias, n, isbf);
      #pragma unroll
      for (int i = 0; i < 4; i++)
        #pragma unroll
        for (int r = 0; r < 4; r++){
          long a = (long)(mbase + i * 16 + r) * ldc + n;
          C[a] = acc[i][j][r] + badd + res[a];
        }
    }
  } else if constexpr (MODE == EP_RELU){
    u16* C = (u16*)Cv;
    #pragma unroll
    for (int j = 0; j < 4; j++){
      int n = nbase + j * 16;
      float badd = ldf(bias, n, isbf);
      #pragma unroll
      for (int i = 0; i < 4; i++)
        #pragma unroll
        for (int r = 0; r < 4; r++)
          C[(long)(mbase + i * 16 + r) * ldc + n] = f2bf(fmaxf(acc[i][j][r] + badd, 0.f));
    }
  }
}

// ---------- 256x256 tile, 8 waves (2M x 4N), BK=32, 2-phase dbuf ----------
// per-wave output 128x64 -> 32 FLOP per LDS byte (2x the 128^2 tile)
template<int MODE, bool GSWAP>
__global__ __launch_bounds__(512, 2) void k_mfma2(
    const u16* __restrict__ A, long sA, int lda,
    const u16* __restrict__ Bt, long sB,
    void* __restrict__ Cv,
    const void* __restrict__ bias,
    const float* __restrict__ res,
    int K, int ldc, float scale,
    const int* __restrict__ dflag)
{
  int isbf = dflag[0];
  int z = blockIdx.z;
  const u16* Ab = A + (long)z * sA;
  const u16* Bb = Bt + (long)z * sB;
  __shared__ __align__(16) u16 As[2][4][256][8];   // 2 x 16 KB
  __shared__ __align__(16) u16 Bs[2][4][256][8];
  int m0 = (GSWAP ? blockIdx.x : blockIdx.y) * 256;
  int n0 = (GSWAP ? blockIdx.y : blockIdx.x) * 256;
  int tid = threadIdx.x;
  int lane = tid & 63, w = tid >> 6;
  int wm = (w >> 2) * 128, wn = (w & 3) * 64;
  int l15 = lane & 15, l4 = lane >> 4;
  int row = tid & 255, ob = tid >> 8;    // staging: row 0..255, octet-base 0..1
  f32x4 zero = {0.f, 0.f, 0.f, 0.f};
  f32x4 acc[8][4];
  #pragma unroll
  for (int i = 0; i < 8; i++)
    #pragma unroll
    for (int j = 0; j < 4; j++) acc[i][j] = zero;

  const long arow0 = (long)(m0 + row) * lda;
  const long brow0 = (long)(n0 + row) * K;

  #define STAGE2(buf, k0) do{ \
    u16* AsF = &As[buf][0][0][0]; \
    u16* BsF = &Bs[buf][0][0][0]; \
    gload16(Ab + arow0 + (k0) + ob * 8,       AsF + (long)(ob * 256 + row) * 8); \
    gload16(Ab + arow0 + (k0) + (ob + 2) * 8, AsF + (long)((ob + 2) * 256 + row) * 8); \
    gload16(Bb + brow0 + (k0) + ob * 8,       BsF + (long)(ob * 256 + row) * 8); \
    gload16(Bb + brow0 + (k0) + (ob + 2) * 8, BsF + (long)((ob + 2) * 256 + row) * 8); \
  }while(0)

  #define COMPUTE2(buf) do{ \
    s16x8 bfr[4]; \
    _Pragma("unroll") \
    for (int j = 0; j < 4; j++) bfr[j] = *(const s16x8*)&Bs[buf][l4][wn + j * 16 + l15][0]; \
    _Pragma("unroll") \
    for (int i = 0; i < 8; i++){ \
      s16x8 af = *(const s16x8*)&As[buf][l4][wm + i * 16 + l15][0]; \
      _Pragma("unroll") \
      for (int j = 0; j < 4; j++) \
        acc[i][j] = mfma16(af, bfr[j], acc[i][j]); \
    } \
  }while(0)

  STAGE2(0, 0);
  __syncthreads();
  for (int k0 = 0; k0 < K; k0 += 64){
    STAGE2(1, k0 + 32);
    COMPUTE2(0);
    __syncthreads();
    if (k0 + 64 < K) STAGE2(0, k0 + 64);
    COMPUTE2(1);
    __syncthreads();
  }
  #undef STAGE2
  #undef COMPUTE2

  int mbase = m0 + wm + l4 * 4;   // C row = mbase + i*16 + r, i<8
  int nbase = n0 + wn + l15;      // C col = nbase + j*16, j<4
  if constexpr (MODE == EP_QCAT || MODE == EP_KCAT){
    u16* C = (u16*)Cv + (long)z * ((long)MTOT * KC);
    #pragma unroll
    for (int j = 0; j < 4; j++){
      int n = nbase + j * 16;
      float badd = ldf(bias, (long)z * DD + n, isbf);
      #pragma unroll
      for (int i = 0; i < 8; i++)
        #pragma unroll
        for (int r = 0; r < 4; r++){
          float qv = acc[i][j][r] + badd;
          u16 hi = f2bf(qv);
          u16 lo = f2bf(qv - bf2f(hi));
          long rb = (long)(mbase + i * 16 + r) * KC;
          C[rb + n] = hi;
          if constexpr (MODE == EP_QCAT){ C[rb + 512 + n] = hi; C[rb + 1024 + n] = lo; }
          else                          { C[rb + 512 + n] = lo; C[rb + 1024 + n] = hi; }
        }
    }
  } else if constexpr (MODE == EP_SCALE){
    float* C = (float*)Cv + (long)z * SS * SS;
    #pragma unroll
    for (int i = 0; i < 8; i++)
      #pragma unroll
      for (int j = 0; j < 4; j++)
        #pragma unroll
        for (int r = 0; r < 4; r++)
          C[(long)(mbase + i * 16 + r) * SS + nbase + j * 16] = acc[i][j][r] * scale;
  } else if constexpr (MODE == EP_VT){
    // vT[(z*8 + b)][d = n][s]; 4 acc regs = 4 consecutive s
    u16* C = (u16*)Cv;
    #pragma unroll
    for (int i = 0; i < 8; i++){
      int mrow = mbase + i * 16;
      int b = mrow >> 9, s = mrow & (SS - 1);
      #pragma unroll
      for (int j = 0; j < 4; j++){
        int n = nbase + j * 16;
        float badd = ldf(bias, (long)z * DD + n, isbf);
        ushort4 pk;
        pk.x = f2bf(acc[i][j][0] + badd); pk.y = f2bf(acc[i][j][1] + badd);
        pk.z = f2bf(acc[i][j][2] + badd); pk.w = f2bf(acc[i][j][3] + badd);
        *(ushort4*)&C[((long)(z * 8 + b) * DD + n) * SS + s] = pk;
      }
    }
  } else if constexpr (MODE == EP_CAT){
    // cat[(b*S + s)][h*D + n]; z = h*8+b
    u16* C = (u16*)Cv;
    int h = z >> 3, b = z & 7;
    #pragma unroll
    for (int i = 0; i < 8; i++){
      int s = mbase + i * 16;
      #pragma unroll
      for (int j = 0; j < 4; j++){
        int n = nbase + j * 16;
        #pragma unroll
        for (int r = 0; r < 4; r++)
          C[((long)b * SS + s + r) * HD + (long)h * DD + n] = f2bf(acc[i][j][r]);
      }
    }
  } else if constexpr (MODE == EP_OUT){
    float* O = (float*)Cv;
    #pragma unroll
    for (int j = 0; j < 4; j++){
      int n = nbase + j * 16;
      float badd = ldf(bias, n, isbf);
      #pragma unroll
      for (int i = 0; i < 8; i++)
        #pragma unroll
        for (int r = 0; r < 4; r++)
          O[(long)(mbase + i * 16 + r) * ldc + n] = acc[i][j][r] + badd;
    }
  }
}

// row softmax f32 -> bf16, 4 rows (one wave each) per block
__global__ __launch_bounds__(256) void k_softmax(const float* __restrict__ S, u16* __restrict__ P)
{
  int row = blockIdx.x * 4 + (threadIdx.x >> 6);
  int lane = threadIdx.x & 63;
  const float* p = S + (long)row * SS + lane * 8;
  float4 v0 = *(const float4*)p;
  float4 v1 = *(const float4*)(p + 4);
  float v[8] = {v0.x, v0.y, v0.z, v0.w, v1.x, v1.y, v1.z, v1.w};
  float mx = v[0];
  #pragma unroll
  for (int i = 1; i < 8; i++) mx = fmaxf(mx, v[i]);
  mx = wave_redmax(mx);
  float e[8], sum = 0.f;
  #pragma unroll
  for (int i = 0; i < 8; i++){ e[i] = expf(v[i] - mx); sum += e[i]; }
  sum = wave_redsum(sum);
  float inv = 1.f / sum;
  u16* q = P + (long)row * SS + lane * 8;
  ushort4 o0, o1;
  o0.x = f2bf(e[0] * inv); o0.y = f2bf(e[1] * inv);
  o0.z = f2bf(e[2] * inv); o0.w = f2bf(e[3] * inv);
  o1.x = f2bf(e[4] * inv); o1.y = f2bf(e[5] * inv);
  o1.z = f2bf(e[6] * inv); o1.w = f2bf(e[7] * inv);
  *(ushort4*)q = o0;
  *(ushort4*)(q + 4) = o1;
}

// LayerNorm f32 -> bf16 (+ optional f32), one wave per row of 512
template<bool WF32>
__global__ __launch_bounds__(256) void k_ln(
    const float* __restrict__ X, const void* __restrict__ g, const void* __restrict__ be,
    u16* __restrict__ Yb, float* __restrict__ Yf, const int* __restrict__ dflag)
{
  int isbf = dflag[0];
  int row = blockIdx.x * 4 + (threadIdx.x >> 6);
  int lane = threadIdx.x & 63;
  const float* p = X + (long)row * DD + lane * 8;
  float4 v0 = *(const float4*)p;
  float4 v1 = *(const float4*)(p + 4);
  float v[8] = {v0.x, v0.y, v0.z, v0.w, v1.x, v1.y, v1.z, v1.w};
  float s = 0.f;
  #pragma unroll
  for (int i = 0; i < 8; i++) s += v[i];
  s = wave_redsum(s);
  float mu = s * (1.f / DD);
  float d_[8], sq = 0.f;
  #pragma unroll
  for (int i = 0; i < 8; i++){ d_[i] = v[i] - mu; sq += d_[i] * d_[i]; }
  sq = wave_redsum(sq);
  float rs = 1.f / sqrtf(sq * (1.f / DD) + 1e-5f);
  #pragma unroll
  for (int i = 0; i < 8; i++){
    int dd = lane * 8 + i;
    float y = ldf(g, dd, isbf) * d_[i] * rs + ldf(be, dd, isbf);
    Yb[(long)row * DD + dd] = f2bf(y);
    if (WF32) Yf[(long)row * DD + dd] = y;
  }
}

extern "C" void kernel_launch(void* const* d_in, const int* in_sizes, int n_in,
                              void* d_out, int out_size, void* d_ws, size_t ws_size,
                              hipStream_t stream)
{
  const int* tokens = (const int*)d_in[0];
  const void* emb = d_in[1];
  const void* pe  = d_in[2];
  const void* Wq  = d_in[3];
  const void* bq  = d_in[4];
  const void* Wk  = d_in[5];
  const void* bk  = d_in[6];
  const void* Wv  = d_in[7];
  const void* bv  = d_in[8];
  const void* Wo  = d_in[9];
  const void* bo  = d_in[10];
  const void* g1  = d_in[11];
  const void* be1 = d_in[12];
  const void* W1  = d_in[13];
  const void* b1  = d_in[14];
  const void* W2  = d_in[15];
  const void* b2  = d_in[16];
  const void* g2  = d_in[17];
  const void* be2 = d_in[18];
  const void* Wf  = d_in[19];
  const void* bfb = d_in[20];
  float* out = (float*)d_out;   // reference output dtype = float32
  char* ws = (char*)d_ws;
  char* DO = (char*)d_out;

  const size_t MB = 1ull << 20;
  // ---- d_ws (39.3 MiB; <=69 MiB evidenced safe) ----
  int* dflag = (int*)ws;
  u16* x2b   = (u16*)(ws + 1 * MB);        // [1,5)
  u16* WfT   = (u16*)(ws + 8 * MB);        // [8,39.25)  bf16 [32000][512]

  // ---- d_out as scratch (452 of 500 MiB; all dead before logits) ----
  float* x      = (float*)(DO + 0 * MB);    // [0,8)
  u16*   xm_cat = (u16*)(DO + 8 * MB);      // [8,20)    [4096][1536] = [xh|xh|xl]
  u16*   Wq_cat = (u16*)(DO + 20 * MB);     // [20,32)   [8][512][1536] = [wh|wl|wh]
  u16*   Wk_cat = (u16*)(DO + 32 * MB);     // [32,44)
  u16*   WvT    = (u16*)(DO + 44 * MB);     // [44,48)   [8][512][512]
  u16*   WoT    = (u16*)(DO + 48 * MB);     // [48,52)   [512][4096]
  u16*   W1T    = (u16*)(DO + 52 * MB);     // [52,54)   [2048][512]
  u16*   W2T    = (u16*)(DO + 54 * MB);     // [54,56)   [512][2048]
  u16*   q_cat  = (u16*)(DO + 56 * MB);     // [56,152)  [8][4096][1536] = [qh|qh|ql]
  u16*   k_cat  = (u16*)(DO + 152 * MB);    // [152,248) [8][4096][1536] = [kh|kl|kh]
  float* sc     = (float*)(DO + 248 * MB);  // [248,312) [64][512][512]
  u16*   attn   = (u16*)(DO + 312 * MB);    // [312,344)
  u16*   vT     = (u16*)(DO + 344 * MB);    // [344,376) [64][512 d][512 s]
  u16*   cat    = (u16*)(DO + 376 * MB);    // [376,408) [4096][4096]
  float* proj   = (float*)(DO + 408 * MB);  // [408,416)
  float* x1f    = (float*)(DO + 416 * MB);  // [416,424)
  u16*   x1b    = (u16*)(DO + 424 * MB);    // [424,428)
  u16*   ff1    = (u16*)(DO + 428 * MB);    // [428,444) [4096][2048]
  float* ff2    = (float*)(DO + 444 * MB);  // [444,452)

  const float scale = 0.04419417382415922f;  // 1/sqrt(512)
  const long HSL = 262144;                   // 512*512
  const long KSL = (long)DD * KC;            // weight-cat slice
  const long QSL = (long)SS * KC;            // q/k-cat per z=(h*8+b)

  k_dflag<<<1, 1, 0, stream>>>(pe, dflag);
  k_embed<<<dim3(4096), 256, 0, stream>>>(tokens, emb, pe, x, xm_cat, dflag);

  // one-time weight prep
  k_wsplitT<<<dim3(16, 16, 8), 256, 0, stream>>>(Wq, Wq_cat, dflag);
  k_wsplitT<<<dim3(16, 16, 8), 256, 0, stream>>>(Wk, Wk_cat, dflag);
  k_transT<<<dim3(16, 16, 8), 256, 0, stream>>>(Wv, WvT, 512, 512, dflag);
  k_transT<<<dim3(16, 128, 1), 256, 0, stream>>>(Wo, WoT, 4096, 512, dflag);
  k_transT<<<dim3(64, 16, 1), 256, 0, stream>>>(W1, W1T, 512, 2048, dflag);
  k_transT<<<dim3(16, 64, 1), 256, 0, stream>>>(W2, W2T, 2048, 512, dflag);
  k_transT<<<dim3(1000, 16, 1), 256, 0, stream>>>(Wf, WfT, 512, 32000, dflag);

  // q/k projections, exact via split-concat K=1536 (256^2 tile)
  k_mfma2<EP_QCAT, false><<<dim3(2, 16, 8), 512, 0, stream>>>(
      xm_cat, 0, KC, Wq_cat, KSL, q_cat, bq, nullptr, KC, 0, 0.f, dflag);
  k_mfma2<EP_KCAT, false><<<dim3(2, 16, 8), 512, 0, stream>>>(
      xm_cat, 0, KC, Wk_cat, KSL, k_cat, bk, nullptr, KC, 0, 0.f, dflag);
  // v projection (bf16-hi input is band0 of xm_cat, lda=1536)
  k_mfma2<EP_VT, false><<<dim3(2, 16, 8), 512, 0, stream>>>(
      xm_cat, 0, KC, WvT, HSL, vT, bv, nullptr, DD, 0, 0.f, dflag);

  // scores = q_cat . k_cat^T * scale (exact to ~2^-16), z = h*8+b
  k_mfma2<EP_SCALE, false><<<dim3(2, 2, 64), 512, 0, stream>>>(
      q_cat, QSL, KC, k_cat, QSL, sc, nullptr, nullptr, KC, 0, scale, dflag);
  k_softmax<<<dim3(8192), 256, 0, stream>>>(sc, attn);

  // o = attn @ v -> cat (torch.cat head order)
  k_mfma2<EP_CAT, false><<<dim3(2, 2, 64), 512, 0, stream>>>(
      attn, HSL, SS, vT, HSL, cat, nullptr, nullptr, SS, 0, 0.f, dflag);

  // proj = cat @ Wo + bo + x (128^2 kernel: N=512 needs more blocks)
  k_mfma<EP_F32RES, false><<<dim3(4, 32, 1), 256, 0, stream>>>(
      cat, 0, HD, WoT, 0, proj, bo, x, HD, DD, 0.f, dflag);
  k_ln<true><<<dim3(1024), 256, 0, stream>>>(proj, g1, be1, x1b, x1f, dflag);

  // ff = relu(x1 @ W1 + b1) @ W2 + b2 + x1
  k_mfma<EP_RELU, false><<<dim3(16, 32, 1), 256, 0, stream>>>(
      x1b, 0, DD, W1T, 0, ff1, b1, nullptr, DD, NFF, 0.f, dflag);
  k_mfma<EP_F32RES, false><<<dim3(4, 32, 1), 256, 0, stream>>>(
      ff1, 0, NFF, W2T, 0, ff2, b2, x1f, NFF, DD, 0.f, dflag);
  k_ln<false><<<dim3(1024), 256, 0, stream>>>(ff2, g2, be2, x2b, nullptr, dflag);

  // logits = x2 @ Wf + bf -> f32 out (256^2, GSWAP: 16 m-tiles share Wf cols in L2)
  k_mfma2<EP_OUT, true><<<dim3(16, 125, 1), 512, 0, stream>>>(
      x2b, 0, DD, WfT, 0, out, bfb, nullptr, DD, VV, 0.f, dflag);
}